// Round 3
// baseline (558.792 us; speedup 1.0000x reference)
//
#include <hip/hip_runtime.h>
#include <cstdint>

#define L_SEQ 2304
#define CDIM  512
#define NHEADS 8
#define HD    64
#define LL    ((size_t)L_SEQ * L_SEQ)
#define ROWS_TOT (16 * L_SEQ)   // 2 batches * 8 heads * L rows = 36864

typedef short  s8v  __attribute__((ext_vector_type(8)));
typedef float  f4v  __attribute__((ext_vector_type(4)));

__device__ __forceinline__ ushort f2bf(float f) {
    union { float f; uint32_t u; } v; v.f = f;
    uint32_t u = v.u;
    uint32_t r = (u + 0x7FFFu + ((u >> 16) & 1u)) >> 16;
    return (ushort)r;
}

// ==================================================================
// QKV projection -> bf16 outputs. q,k in (b,h,l,d); v transposed (b,h,d,l).
// Q pre-scaled by 0.125 (exact pow2). grid (36, 8, 6), block 256.
__global__ __launch_bounds__(256) void qkv_gemm(
    const float* __restrict__ x, const float* __restrict__ pos,
    const float* __restrict__ Wq, const float* __restrict__ bq,
    const float* __restrict__ Wk, const float* __restrict__ bk,
    const float* __restrict__ Wv, const float* __restrict__ bv,
    ushort* __restrict__ q_t, ushort* __restrict__ k_t, ushort* __restrict__ v_t)
{
    const int l0 = blockIdx.x * 64;
    const int o0 = blockIdx.y * 64;
    const int b  = blockIdx.z / 3;
    const int w  = blockIdx.z % 3;
    const float* W    = (w == 0) ? Wq : (w == 1) ? Wk : Wv;
    const float* bias = (w == 0) ? bq : (w == 1) ? bk : bv;

    __shared__ float As[16][68];
    __shared__ float Xs[16][68];

    const int t  = threadIdx.x;
    const int ti = t & 15;
    const int tj = t >> 4;
    float acc[4][4] = {};

    const float* xb = x + (size_t)b * CDIM * L_SEQ;

    for (int c0 = 0; c0 < CDIM; c0 += 16) {
        {
            const int oi = t >> 2;
            const int cc = (t & 3) * 4;
            const float4 wv = *(const float4*)&W[(size_t)(o0 + oi) * CDIM + c0 + cc];
            As[cc + 0][oi] = wv.x;
            As[cc + 1][oi] = wv.y;
            As[cc + 2][oi] = wv.z;
            As[cc + 3][oi] = wv.w;
        }
        {
            const int kk = t >> 4;
            const int j  = (t & 15) * 4;
            const size_t off = (size_t)(c0 + kk) * L_SEQ + l0 + j;
            float4 xv = *(const float4*)&xb[off];
            const float4 pv = *(const float4*)&pos[off];
            xv.x += pv.x; xv.y += pv.y; xv.z += pv.z; xv.w += pv.w;
            *(float4*)&Xs[kk][j] = xv;
        }
        __syncthreads();
        #pragma unroll
        for (int kk = 0; kk < 16; kk++) {
            const float4 a  = *(const float4*)&As[kk][ti * 4];
            const float4 bb = *(const float4*)&Xs[kk][tj * 4];
            const float av[4] = {a.x, a.y, a.z, a.w};
            const float bv4[4] = {bb.x, bb.y, bb.z, bb.w};
            #pragma unroll
            for (int i = 0; i < 4; i++)
                #pragma unroll
                for (int j = 0; j < 4; j++)
                    acc[i][j] += av[i] * bv4[j];
        }
        __syncthreads();
    }

    const int h = o0 >> 6;
    const float4 bi = *(const float4*)&bias[o0 + ti * 4];
    const float bia[4] = {bi.x, bi.y, bi.z, bi.w};

    if (w < 2) {
        // q/k row-major (b,h,l,d), Q scaled by 0.125
        const float sc = (w == 0) ? 0.125f : 1.0f;
        ushort* op = (w == 0 ? q_t : k_t) + ((size_t)b * NHEADS + h) * L_SEQ * HD;
        #pragma unroll
        for (int j = 0; j < 4; j++) {
            const int l = l0 + tj * 4 + j;
            ushort4 st;
            st.x = f2bf((acc[0][j] + bia[0]) * sc);
            st.y = f2bf((acc[1][j] + bia[1]) * sc);
            st.z = f2bf((acc[2][j] + bia[2]) * sc);
            st.w = f2bf((acc[3][j] + bia[3]) * sc);
            *(ushort4*)&op[(size_t)l * HD + ti * 4] = st;
        }
    } else {
        // v transposed (b,h,d,l)
        ushort* op = v_t + ((size_t)b * NHEADS + h) * HD * L_SEQ;
        #pragma unroll
        for (int i = 0; i < 4; i++) {
            const int d = ti * 4 + i;
            ushort4 st;
            st.x = f2bf(acc[i][0] + bia[i]);
            st.y = f2bf(acc[i][1] + bia[i]);
            st.z = f2bf(acc[i][2] + bia[i]);
            st.w = f2bf(acc[i][3] + bia[i]);
            *(ushort4*)&op[(size_t)d * L_SEQ + l0 + tj * 4] = st;
        }
    }
}

// ==================================================================
// MFMA flash attention, split-K across blocks, NO LDS STAGING.
// K/V MFMA B-fragments are loaded directly from global (L2-resident:
// K,V per (b,h) = 294 KB each; head pinned per XCD via id&7; all of a
// block's K/V + mask stream fit the XCD's 4 MB L2). This removes both
// in-loop barriers -> waves are fully independent and pipeline across
// tiles -> and cuts LDS to ~9.7 KB (P buffer + rel table), attacking
// the LDS-residency limit observed at 26 KB/block (~2.3 blocks/CU).
// grid 1152 (1D, XCD-pinned head), block 256 (4 independent waves).
__global__ __launch_bounds__(256) void flash_attn_mfma(
    const ushort* __restrict__ q, const ushort* __restrict__ k,
    const ushort* __restrict__ vt, const int* __restrict__ mask,
    const float* __restrict__ rel_table, float* __restrict__ Opart,
    float* __restrict__ Mpart, float* __restrict__ Lpart)
{
    __shared__ __align__(16) ushort Pb[4 * 16 * 72]; // per-wave P, row-major [16][72]
    __shared__ float rt[65];

    const int t    = threadIdx.x;
    const int id   = blockIdx.x;
    const int h    = id & 7;            // XCD-pinned head
    const int s2   = id >> 3;           // [0,144)
    const int b    = s2 & 1;            // adjacent slots share mask rows (L2 reuse)
    const int half = (s2 >> 1) & 1;     // key half
    const int qb   = s2 >> 2;           // [0,36)
    const int bh   = b * NHEADS + h;
    const int l0   = qb * 64;
    const int w    = t >> 6;
    const int lane = t & 63;
    const int n16  = lane & 15;
    const int q4   = lane >> 4;

    if (t < 65) rt[t] = rel_table[h * 65 + t];

    const ushort* qp = q  + (size_t)bh * L_SEQ * HD;
    const ushort* kp = k  + (size_t)bh * L_SEQ * HD;
    const ushort* vp = vt + (size_t)bh * HD * L_SEQ;
    const int*    mp = mask + (size_t)h * LL;

    // Q A-fragments: A[m=lane&15][k=quad*8+j], rows l0+w*16+n16
    const int qrow = l0 + w * 16 + n16;
    const s8v qA0 = *(const s8v*)&qp[(size_t)qrow * HD + q4 * 8];
    const s8v qA1 = *(const s8v*)&qp[(size_t)qrow * HD + 32 + q4 * 8];

    f4v O[4] = {{0.f,0.f,0.f,0.f},{0.f,0.f,0.f,0.f},{0.f,0.f,0.f,0.f},{0.f,0.f,0.f,0.f}};
    float mrun[4] = {-3e38f, -3e38f, -3e38f, -3e38f};
    float lrun[4] = {0.f, 0.f, 0.f, 0.f};

    const int rowbase = l0 + w * 16 + q4 * 4;   // +r gives the C-layout row
    const int kbase = half * 1152;

    // per-thread fragment base pointers (direct-from-global B-frags)
    const ushort* kq = kp + (size_t)n16 * HD + q4 * 8;      // + (mb+t4*16)*HD + f*32
    const ushort* vq = vp + (size_t)n16 * L_SEQ + q4 * 8;   // + t4*16*L + mb + f*32

    __syncthreads();   // rt ready

    for (int mt = 0; mt < 18; mt++) {
        const int mb = kbase + mt * 64;

        // K B-frags direct from global: B[d=f*32+q4*8+j][key=t4*16+n16]
        //   = kp[(mb+t4*16+n16)*HD + f*32 + q4*8 .. +8]
        s8v kf[4][2];
        #pragma unroll
        for (int t4 = 0; t4 < 4; t4++)
            #pragma unroll
            for (int f = 0; f < 2; f++)
                kf[t4][f] = *(const s8v*)&kq[((size_t)(mb + t4 * 16)) * HD + f * 32];

        // mask loads (issued behind K; consumed after S)
        int mreg[4][4];
        #pragma unroll
        for (int t4 = 0; t4 < 4; t4++)
            #pragma unroll
            for (int r = 0; r < 4; r++)
                mreg[t4][r] = mp[(size_t)(rowbase + r) * L_SEQ + mb + t4 * 16 + n16];

        // S = Q K^T  (C layout: col=lane&15 -> key t4*16+n16, row=q4*4+r)
        f4v S[4];
        #pragma unroll
        for (int t4 = 0; t4 < 4; t4++) {
            f4v acc = {0.f, 0.f, 0.f, 0.f};
            acc = __builtin_amdgcn_mfma_f32_16x16x32_bf16(qA0, kf[t4][0], acc, 0, 0, 0);
            acc = __builtin_amdgcn_mfma_f32_16x16x32_bf16(qA1, kf[t4][1], acc, 0, 0, 0);
            S[t4] = acc;
        }

        // V B-frags direct from global (issued early; consumed in PV):
        //   B[k=f*32+q4*8+j][d=t4*16+n16] = vt[(t4*16+n16)*L + mb + f*32 + q4*8 .. +8]
        s8v vf[4][2];
        #pragma unroll
        for (int t4 = 0; t4 < 4; t4++)
            #pragma unroll
            for (int f = 0; f < 2; f++)
                vf[t4][f] = *(const s8v*)&vq[(size_t)(t4 * 16) * L_SEQ + mb + f * 32];

        // relative positional bias (then mask -> exactly -1e9, matching ref order)
        #pragma unroll
        for (int t4 = 0; t4 < 4; t4++) {
            const int A = (l0 + w * 16) - (mb + t4 * 16);
            if (A >= 47) {
                const float bu = rt[64];
                #pragma unroll
                for (int r = 0; r < 4; r++) S[t4][r] += bu;
            } else if (A <= -47) {
                const float bu = rt[0];
                #pragma unroll
                for (int r = 0; r < 4; r++) S[t4][r] += bu;
            } else {
                #pragma unroll
                for (int r = 0; r < 4; r++) {
                    int dix = A + q4 * 4 + r - n16;
                    dix = min(max(dix, -32), 32) + 32;
                    S[t4][r] += rt[dix];
                }
            }
            #pragma unroll
            for (int r = 0; r < 4; r++)
                if (mreg[t4][r] == 0) S[t4][r] = -1e9f;
        }

        // online softmax per row (row stats replicated over 16 lanes of quad)
        float mx[4];
        #pragma unroll
        for (int r = 0; r < 4; r++) {
            float m0 = fmaxf(fmaxf(S[0][r], S[1][r]), fmaxf(S[2][r], S[3][r]));
            m0 = fmaxf(m0, __shfl_xor(m0, 1));
            m0 = fmaxf(m0, __shfl_xor(m0, 2));
            m0 = fmaxf(m0, __shfl_xor(m0, 4));
            m0 = fmaxf(m0, __shfl_xor(m0, 8));
            mx[r] = m0;
        }
        float al[4];
        #pragma unroll
        for (int r = 0; r < 4; r++) {
            const float mn = fmaxf(mrun[r], mx[r]);
            al[r] = __expf(mrun[r] - mn);
            mrun[r] = mn;
            float sum = 0.f;
            #pragma unroll
            for (int t4 = 0; t4 < 4; t4++) {
                const float p = __expf(S[t4][r] - mn);
                S[t4][r] = p;
                sum += p;
                Pb[w * 1152 + (q4 * 4 + r) * 72 + t4 * 16 + n16] = f2bf(p);
            }
            sum += __shfl_xor(sum, 1);
            sum += __shfl_xor(sum, 2);
            sum += __shfl_xor(sum, 4);
            sum += __shfl_xor(sum, 8);
            lrun[r] = lrun[r] * al[r] + sum;
        }

        // rescale O, then O += P V   (per-wave Pb: same-wave dep, no barrier)
        const s8v pf0 = *(const s8v*)&Pb[w * 1152 + n16 * 72 + q4 * 8];
        const s8v pf1 = *(const s8v*)&Pb[w * 1152 + n16 * 72 + 32 + q4 * 8];
        #pragma unroll
        for (int t4 = 0; t4 < 4; t4++) {
            f4v o = O[t4];
            #pragma unroll
            for (int r = 0; r < 4; r++) o[r] *= al[r];
            o = __builtin_amdgcn_mfma_f32_16x16x32_bf16(pf0, vf[t4][0], o, 0, 0, 0);
            o = __builtin_amdgcn_mfma_f32_16x16x32_bf16(pf1, vf[t4][1], o, 0, 0, 0);
            O[t4] = o;
        }
    }

    // write UNNORMALIZED partial O + per-row stats for this key-half
    float* op = Opart + ((size_t)half * 16 + bh) * L_SEQ * HD;
    #pragma unroll
    for (int r = 0; r < 4; r++) {
        const size_t row = (size_t)(rowbase + r) * HD;
        #pragma unroll
        for (int t4 = 0; t4 < 4; t4++)
            op[row + t4 * 16 + n16] = O[t4][r];
    }
    if (n16 == 0) {
        const size_t sb = (size_t)half * ROWS_TOT + (size_t)bh * L_SEQ;
        #pragma unroll
        for (int r = 0; r < 4; r++) {
            Mpart[sb + rowbase + r] = mrun[r];
            Lpart[sb + rowbase + r] = lrun[r];
        }
    }
}

// ==================================================================
// Merge the two key-half partials. In-place: result lands in half 0 of O01.
// grid 2304, block 256 — one float4 per thread.
__global__ __launch_bounds__(256) void combine_kernel(
    float* __restrict__ O01, const float* __restrict__ Mp,
    const float* __restrict__ Lp)
{
    const int i   = blockIdx.x * 256 + threadIdx.x;  // float4 idx, 589824 total
    const int row = i >> 4;                          // bh*L + l
    const float m0 = Mp[row], m1 = Mp[ROWS_TOT + row];
    const float l0 = Lp[row], l1 = Lp[ROWS_TOT + row];
    const float M  = fmaxf(m0, m1);
    const float w0 = __expf(m0 - M);
    const float w1 = __expf(m1 - M);
    const float inv = 1.0f / (l0 * w0 + l1 * w1);
    const float f0 = w0 * inv;
    const float f1 = w1 * inv;
    float4 a = ((const float4*)O01)[i];
    const float4 c = ((const float4*)O01)[(size_t)ROWS_TOT * 16 + i];
    a.x = a.x * f0 + c.x * f1;
    a.y = a.y * f0 + c.y * f1;
    a.z = a.z * f0 + c.z * f1;
    a.w = a.w * f0 + c.w * f1;
    ((float4*)O01)[i] = a;
}

// ==================================================================
// Output projection + bias + residual (fp32). grid (36, 8, 2), block 256.
__global__ __launch_bounds__(256) void out_gemm(
    const float* __restrict__ attn, const float* __restrict__ Wo,
    const float* __restrict__ bo, const float* __restrict__ x,
    float* __restrict__ y)
{
    const int l0 = blockIdx.x * 64;
    const int o0 = blockIdx.y * 64;
    const int b  = blockIdx.z;

    __shared__ float As[16][68];
    __shared__ float Xs[16][68];

    const int t  = threadIdx.x;
    const int ti = t & 15;
    const int tj = t >> 4;
    float acc[4][4] = {};

    const float* ab = attn + (size_t)b * NHEADS * L_SEQ * HD;

    for (int c0 = 0; c0 < CDIM; c0 += 16) {
        {
            const int oi = t >> 2;
            const int cc = (t & 3) * 4;
            const float4 wv = *(const float4*)&Wo[(size_t)(o0 + oi) * CDIM + c0 + cc];
            As[cc + 0][oi] = wv.x;
            As[cc + 1][oi] = wv.y;
            As[cc + 2][oi] = wv.z;
            As[cc + 3][oi] = wv.w;
        }
        {
            const int j   = t & 63;
            const int kkb = (t >> 6) * 4;
            const int c   = c0 + kkb;
            const int hh  = c >> 6;
            const int dd  = c & 63;
            const float4 av = *(const float4*)&ab[((size_t)hh * L_SEQ + l0 + j) * HD + dd];
            Xs[kkb + 0][j] = av.x;
            Xs[kkb + 1][j] = av.y;
            Xs[kkb + 2][j] = av.z;
            Xs[kkb + 3][j] = av.w;
        }
        __syncthreads();
        #pragma unroll
        for (int kk = 0; kk < 16; kk++) {
            const float4 a  = *(const float4*)&As[kk][ti * 4];
            const float4 bb = *(const float4*)&Xs[kk][tj * 4];
            const float av[4] = {a.x, a.y, a.z, a.w};
            const float bv4[4] = {bb.x, bb.y, bb.z, bb.w};
            #pragma unroll
            for (int i = 0; i < 4; i++)
                #pragma unroll
                for (int j = 0; j < 4; j++)
                    acc[i][j] += av[i] * bv4[j];
        }
        __syncthreads();
    }

    const float4 bi = *(const float4*)&bo[o0 + ti * 4];
    const float bia[4] = {bi.x, bi.y, bi.z, bi.w};
    #pragma unroll
    for (int i = 0; i < 4; i++) {
        const int o = o0 + ti * 4 + i;
        const size_t off = ((size_t)b * CDIM + o) * L_SEQ + l0 + tj * 4;
        const float4 xv = *(const float4*)&x[off];
        float4 st;
        st.x = acc[i][0] + bia[i] + xv.x;
        st.y = acc[i][1] + bia[i] + xv.y;
        st.z = acc[i][2] + bia[i] + xv.z;
        st.w = acc[i][3] + bia[i] + xv.w;
        *(float4*)&y[off] = st;
    }
}

// ==================================================================
__global__ __launch_bounds__(256) void ln_kernel(
    float* __restrict__ y, const float* __restrict__ gamma,
    const float* __restrict__ beta)
{
    const int t  = threadIdx.x;
    const int pi = t & 63;
    const int g  = t >> 6;
    const int pos = blockIdx.x * 64 + pi;
    const int b = (pos >= L_SEQ) ? 1 : 0;
    const int l = pos - b * L_SEQ;
    float* col = y + (size_t)b * CDIM * L_SEQ + l;

    float s = 0.f, sq = 0.f;
    for (int c = g * 128; c < g * 128 + 128; c++) {
        const float v = col[(size_t)c * L_SEQ];
        s += v; sq += v * v;
    }
    __shared__ float S1[4][64];
    __shared__ float S2[4][64];
    S1[g][pi] = s; S2[g][pi] = sq;
    __syncthreads();
    if (g == 0) {
        s  = S1[0][pi] + S1[1][pi] + S1[2][pi] + S1[3][pi];
        sq = S2[0][pi] + S2[1][pi] + S2[2][pi] + S2[3][pi];
        const float mu = s * (1.0f / CDIM);
        const float var = sq * (1.0f / CDIM) - mu * mu;
        S1[0][pi] = mu;
        S2[0][pi] = rsqrtf(var + 1e-5f);
    }
    __syncthreads();
    const float mu = S1[0][pi];
    const float rs = S2[0][pi];
    for (int c = g * 128; c < g * 128 + 128; c++) {
        const float v = col[(size_t)c * L_SEQ];
        col[(size_t)c * L_SEQ] = (v - mu) * rs * gamma[c] + beta[c];
    }
}

// ==================================================================
extern "C" void kernel_launch(void* const* d_in, const int* in_sizes, int n_in,
                              void* d_out, int out_size, void* d_ws, size_t ws_size,
                              hipStream_t stream) {
    const float* x    = (const float*)d_in[0];
    const int* mask   = (const int*)d_in[1];
    const float* pos  = (const float*)d_in[2];
    const float* Wq   = (const float*)d_in[3];
    const float* bq   = (const float*)d_in[4];
    const float* Wk   = (const float*)d_in[5];
    const float* bk   = (const float*)d_in[6];
    const float* Wv   = (const float*)d_in[7];
    const float* bv   = (const float*)d_in[8];
    const float* Wo   = (const float*)d_in[9];
    const float* bo   = (const float*)d_in[10];
    const float* rel  = (const float*)d_in[11];
    const float* gam  = (const float*)d_in[12];
    const float* bet  = (const float*)d_in[13];

    const size_t per = (size_t)2 * NHEADS * L_SEQ * HD;  // 2359296 elems
    ushort* qw = (ushort*)d_ws;
    ushort* kw = qw + per;
    ushort* vw = kw + per;
    float* Opart = (float*)(vw + per);        // [2][16][L][64] fp32, 18.9 MB
    float* Mpart = Opart + 2 * per;           // [2][36864]
    float* Lpart = Mpart + 2 * ROWS_TOT;      // [2][36864]
    float* attn  = Opart;                     // combine merges in-place into half 0
    float* y     = (float*)d_out;

    dim3 g1(L_SEQ / 64, CDIM / 64, 2 * 3);
    qkv_gemm<<<g1, 256, 0, stream>>>(x, pos, Wq, bq, Wk, bk, Wv, bv, qw, kw, vw);

    flash_attn_mfma<<<dim3(1152), 256, 0, stream>>>(qw, kw, vw, mask, rel,
                                                    Opart, Mpart, Lpart);

    combine_kernel<<<dim3(2304), 256, 0, stream>>>(Opart, Mpart, Lpart);

    dim3 g3(L_SEQ / 64, CDIM / 64, 2);
    out_gemm<<<g3, 256, 0, stream>>>(attn, Wo, bo, x, y);

    ln_kernel<<<(2 * L_SEQ) / 64, 256, 0, stream>>>(y, gam, bet);
}

// Round 5
// 453.473 us; speedup vs baseline: 1.2322x; 1.2322x over previous
//
#include <hip/hip_runtime.h>
#include <cstdint>

#define L_SEQ 2304
#define CDIM  512
#define NHEADS 8
#define HD    64
#define LL    ((size_t)L_SEQ * L_SEQ)
#define ROWS_TOT (16 * L_SEQ)            // 2 batches * 8 heads * L rows
#define PERBL ((size_t)2 * L_SEQ * 512)  // elems in one [2][L][512] plane

typedef short  s8v  __attribute__((ext_vector_type(8)));
typedef float  f4v  __attribute__((ext_vector_type(4)));

__device__ __forceinline__ ushort f2bf(float f) {
    union { float f; uint32_t u; } v; v.f = f;
    uint32_t u = v.u;
    uint32_t r = (u + 0x7FFFu + ((u >> 16) & 1u)) >> 16;
    return (ushort)r;
}

__device__ __forceinline__ float bf2f(ushort u) {
    union { uint32_t u; float f; } v; v.u = (uint32_t)u << 16;
    return v.f;
}

// ==================================================================
// Convert Wq,Wk,Wv,Wo (512x512 fp32, row-major (o,c)) to bf16.
// grid 1024, block 256 — one float4 per thread.
__global__ __launch_bounds__(256) void prep_w(
    const float* __restrict__ Wq, const float* __restrict__ Wk,
    const float* __restrict__ Wv, const float* __restrict__ Wo,
    ushort* __restrict__ wb)
{
    const int i   = blockIdx.x * 256 + threadIdx.x;  // 262144 float4 total
    const int mat = i >> 16;                         // 65536 float4 per mat
    const int j   = i & 65535;
    const float* src = (mat == 0) ? Wq : (mat == 1) ? Wk : (mat == 2) ? Wv : Wo;
    const float4 w = ((const float4*)src)[j];
    ushort4 o;
    o.x = f2bf(w.x); o.y = f2bf(w.y); o.z = f2bf(w.z); o.w = f2bf(w.w);
    ((ushort4*)(wb + (size_t)mat * 262144))[j] = o;
}

// ==================================================================
// XT[b][l][c] = bf16(x[b][c][l] + pos[c][l]).  64x64 LDS tile transpose.
// grid (36, 8, 2), block 256.
__global__ __launch_bounds__(256) void xpose(
    const float* __restrict__ x, const float* __restrict__ pos,
    ushort* __restrict__ xt)
{
    __shared__ ushort T[64][72];
    const int l0 = blockIdx.x * 64;
    const int c0 = blockIdx.y * 64;
    const int b  = blockIdx.z;
    const int t  = threadIdx.x;
    const int cc = t >> 2;
    const int l4 = (t & 3) * 16;
    const size_t off  = ((size_t)b * CDIM + c0 + cc) * L_SEQ + l0 + l4;
    const size_t poff = (size_t)(c0 + cc) * L_SEQ + l0 + l4;
    #pragma unroll
    for (int j4 = 0; j4 < 4; j4++) {
        const float4 xv = *(const float4*)&x[off + j4 * 4];
        const float4 pv = *(const float4*)&pos[poff + j4 * 4];
        T[cc][l4 + j4 * 4 + 0] = f2bf(xv.x + pv.x);
        T[cc][l4 + j4 * 4 + 1] = f2bf(xv.y + pv.y);
        T[cc][l4 + j4 * 4 + 2] = f2bf(xv.z + pv.z);
        T[cc][l4 + j4 * 4 + 3] = f2bf(xv.w + pv.w);
    }
    __syncthreads();
    const int lr = t >> 2;
    const int c4 = (t & 3) * 16;
    ushort o[16];
    #pragma unroll
    for (int j = 0; j < 16; j++) o[j] = T[c4 + j][lr];
    ushort* dst = &xt[((size_t)b * L_SEQ + l0 + lr) * 512 + c0 + c4];
    *(ushort4*)&dst[0]  = *(ushort4*)&o[0];
    *(ushort4*)&dst[4]  = *(ushort4*)&o[4];
    *(ushort4*)&dst[8]  = *(ushort4*)&o[8];
    *(ushort4*)&dst[12] = *(ushort4*)&o[12];
}

// ==================================================================
// QKV projection via bf16 MFMA, no LDS. D[l][o] = sum_c XT[l][c]*W[o][c].
// A-frag: lane(m=n16) holds XT[l0+w*16+n16][kc+q4*8..+8] (16B contiguous).
// B-frag: lane(n=n16) holds W[o0+t4*16+n16][kc+q4*8..+8] (16B contiguous).
// q,k written (b,h,l,d) bf16 (Q scaled 0.125); v written (b,h,d,l) bf16.
// grid (36, 8, 6), block 256 (4 waves, each 16 l-rows x 64 o).
__global__ __launch_bounds__(256) void qkv_mfma(
    const ushort* __restrict__ xt, const ushort* __restrict__ wb,
    const float* __restrict__ bq, const float* __restrict__ bk,
    const float* __restrict__ bv,
    ushort* __restrict__ q_t, ushort* __restrict__ k_t, ushort* __restrict__ v_t)
{
    const int l0  = blockIdx.x * 64;
    const int o0  = blockIdx.y * 64;     // == h*64
    const int b   = blockIdx.z / 3;
    const int mat = blockIdx.z % 3;
    const int t = threadIdx.x, w = t >> 6, lane = t & 63;
    const int n16 = lane & 15, q4 = lane >> 4;

    const ushort* A = xt + ((size_t)b * L_SEQ + l0 + w * 16 + n16) * 512 + q4 * 8;
    const ushort* B = wb + (size_t)mat * 262144 + (size_t)(o0 + n16) * 512 + q4 * 8;

    f4v acc[4] = {{0.f,0.f,0.f,0.f},{0.f,0.f,0.f,0.f},{0.f,0.f,0.f,0.f},{0.f,0.f,0.f,0.f}};
    #pragma unroll
    for (int kc = 0; kc < 512; kc += 32) {
        const s8v a = *(const s8v*)&A[kc];
        #pragma unroll
        for (int t4 = 0; t4 < 4; t4++) {
            const s8v bf = *(const s8v*)&B[(size_t)(t4 * 16) * 512 + kc];
            acc[t4] = __builtin_amdgcn_mfma_f32_16x16x32_bf16(a, bf, acc[t4], 0, 0, 0);
        }
    }

    const float* bias = (mat == 0) ? bq : (mat == 1) ? bk : bv;
    const int h = o0 >> 6;
    const int rowbase = l0 + w * 16 + q4 * 4;

    if (mat < 2) {
        const float sc = (mat == 0) ? 0.125f : 1.0f;
        ushort* op = (mat == 0 ? q_t : k_t) + ((size_t)(b * NHEADS + h)) * L_SEQ * HD;
        #pragma unroll
        for (int t4 = 0; t4 < 4; t4++) {
            const float bi = bias[o0 + t4 * 16 + n16];
            #pragma unroll
            for (int r = 0; r < 4; r++)
                op[(size_t)(rowbase + r) * HD + t4 * 16 + n16] = f2bf((acc[t4][r] + bi) * sc);
        }
    } else {
        ushort* op = v_t + ((size_t)(b * NHEADS + h)) * HD * L_SEQ;
        #pragma unroll
        for (int t4 = 0; t4 < 4; t4++) {
            const float bi = bias[o0 + t4 * 16 + n16];
            ushort4 st;
            st.x = f2bf(acc[t4][0] + bi);
            st.y = f2bf(acc[t4][1] + bi);
            st.z = f2bf(acc[t4][2] + bi);
            st.w = f2bf(acc[t4][3] + bi);
            *(ushort4*)&op[(size_t)(t4 * 16 + n16) * L_SEQ + rowbase] = st;
        }
    }
}

// ==================================================================
// MFMA flash attention, split-K across blocks (round-2 staged structure,
// best measured). Partial O written bf16 in (b, l, c=h*64+d) layout so the
// output projection can consume it as an MFMA A-operand after combine.
// (bf16 partials: they get rounded to bf16 at combine anyway; this keeps
// workspace at 31.0 MB, under the proven-safe 33.6 MB footprint.)
// grid 1152 (1D, XCD-pinned head), block 256.
__global__ __launch_bounds__(256) void flash_attn_mfma(
    const ushort* __restrict__ q, const ushort* __restrict__ k,
    const ushort* __restrict__ vt, const int* __restrict__ mask,
    const float* __restrict__ rel_table, ushort* __restrict__ Opart,
    float* __restrict__ Mpart, float* __restrict__ Lpart)
{
    __shared__ __align__(16) ushort Kf[512 * 8];   // B-frags for S
    __shared__ __align__(16) ushort Vf[512 * 8];   // B-frags for PV
    __shared__ __align__(16) ushort Pb[4 * 16 * 72]; // per-wave P, row-major [16][72]
    __shared__ float rt[65];

    const int t    = threadIdx.x;
    const int id   = blockIdx.x;
    const int h    = id & 7;            // XCD-pinned head
    const int s2   = id >> 3;           // [0,144)
    const int b    = s2 & 1;            // adjacent slots share mask rows (L2 reuse)
    const int half = (s2 >> 1) & 1;     // key half
    const int qb   = s2 >> 2;           // [0,36)
    const int bh   = b * NHEADS + h;
    const int l0   = qb * 64;
    const int w    = t >> 6;
    const int lane = t & 63;
    const int n16  = lane & 15;
    const int q4   = lane >> 4;

    if (t < 65) rt[t] = rel_table[h * 65 + t];

    const ushort* qp = q  + (size_t)bh * L_SEQ * HD;
    const ushort* kp = k  + (size_t)bh * L_SEQ * HD;
    const ushort* vp = vt + (size_t)bh * HD * L_SEQ;
    const int*    mp = mask + (size_t)h * LL;

    // Q A-fragments: A[m=lane&15][k=quad*8+j], rows l0+w*16+n16
    const int qrow = l0 + w * 16 + n16;
    const s8v qA0 = *(const s8v*)&qp[(size_t)qrow * HD + q4 * 8];
    const s8v qA1 = *(const s8v*)&qp[(size_t)qrow * HD + 32 + q4 * 8];

    f4v O[4] = {{0.f,0.f,0.f,0.f},{0.f,0.f,0.f,0.f},{0.f,0.f,0.f,0.f},{0.f,0.f,0.f,0.f}};
    float mrun[4] = {-3e38f, -3e38f, -3e38f, -3e38f};
    float lrun[4] = {0.f, 0.f, 0.f, 0.f};

    // precompute this thread's two staging chunk decodes (c = t, t+256)
    int sT[2], sS[2], sQ[2], sN[2];
    #pragma unroll
    for (int cc = 0; cc < 2; cc++) {
        const int c = t + cc * 256;
        const int g = c >> 6;
        sT[cc] = g >> 1; sS[cc] = g & 1;
        sQ[cc] = (c >> 4) & 3; sN[cc] = c & 15;
    }

    const int rowbase = l0 + w * 16 + q4 * 4;   // +r gives the C-layout row
    const int kbase = half * 1152;

    for (int mt = 0; mt < 18; mt++) {
        const int mb = kbase + mt * 64;
        __syncthreads();   // WAR: previous tile's reads done before restage
        #pragma unroll
        for (int cc = 0; cc < 2; cc++) {
            const int c = t + cc * 256;
            const int key = sT[cc] * 16 + sN[cc];
            const int d0  = sS[cc] * 32 + sQ[cc] * 8;
            *(s8v*)&Kf[c * 8] = *(const s8v*)&kp[(size_t)(mb + key) * HD + d0];
            // V chunk: element j = V[mb + d0+j][sT*16+sN] = vt[(sT*16+sN)][mb+d0+j]
            const int dd = sT[cc] * 16 + sN[cc];
            *(s8v*)&Vf[c * 8] = *(const s8v*)&vp[(size_t)dd * L_SEQ + mb + d0];
        }
        __syncthreads();

        // mask loads (issue early; int32 per harness bool convention)
        int mreg[4][4];
        #pragma unroll
        for (int t4 = 0; t4 < 4; t4++)
            #pragma unroll
            for (int r = 0; r < 4; r++)
                mreg[t4][r] = mp[(size_t)(rowbase + r) * L_SEQ + mb + t4 * 16 + n16];

        // S = Q K^T  (C layout: col=lane&15 -> key t4*16+n16, row=q4*4+r)
        f4v S[4];
        #pragma unroll
        for (int t4 = 0; t4 < 4; t4++) {
            const s8v b0 = *(const s8v*)&Kf[((t4 * 2 + 0) * 64 + lane) * 8];
            const s8v b1 = *(const s8v*)&Kf[((t4 * 2 + 1) * 64 + lane) * 8];
            f4v acc = {0.f, 0.f, 0.f, 0.f};
            acc = __builtin_amdgcn_mfma_f32_16x16x32_bf16(qA0, b0, acc, 0, 0, 0);
            acc = __builtin_amdgcn_mfma_f32_16x16x32_bf16(qA1, b1, acc, 0, 0, 0);
            S[t4] = acc;
        }

        // relative positional bias (then mask -> exactly -1e9, matching ref order)
        #pragma unroll
        for (int t4 = 0; t4 < 4; t4++) {
            const int A = (l0 + w * 16) - (mb + t4 * 16);
            if (A >= 47) {
                const float bu = rt[64];
                #pragma unroll
                for (int r = 0; r < 4; r++) S[t4][r] += bu;
            } else if (A <= -47) {
                const float bu = rt[0];
                #pragma unroll
                for (int r = 0; r < 4; r++) S[t4][r] += bu;
            } else {
                #pragma unroll
                for (int r = 0; r < 4; r++) {
                    int dix = A + q4 * 4 + r - n16;
                    dix = min(max(dix, -32), 32) + 32;
                    S[t4][r] += rt[dix];
                }
            }
            #pragma unroll
            for (int r = 0; r < 4; r++)
                if (mreg[t4][r] == 0) S[t4][r] = -1e9f;
        }

        // online softmax per row (row stats replicated over 16 lanes of quad)
        float mx[4];
        #pragma unroll
        for (int r = 0; r < 4; r++) {
            float m0 = fmaxf(fmaxf(S[0][r], S[1][r]), fmaxf(S[2][r], S[3][r]));
            m0 = fmaxf(m0, __shfl_xor(m0, 1));
            m0 = fmaxf(m0, __shfl_xor(m0, 2));
            m0 = fmaxf(m0, __shfl_xor(m0, 4));
            m0 = fmaxf(m0, __shfl_xor(m0, 8));
            mx[r] = m0;
        }
        float al[4];
        #pragma unroll
        for (int r = 0; r < 4; r++) {
            const float mn = fmaxf(mrun[r], mx[r]);
            al[r] = __expf(mrun[r] - mn);
            mrun[r] = mn;
            float sum = 0.f;
            #pragma unroll
            for (int t4 = 0; t4 < 4; t4++) {
                const float p = __expf(S[t4][r] - mn);
                S[t4][r] = p;
                sum += p;
                Pb[w * 1152 + (q4 * 4 + r) * 72 + t4 * 16 + n16] = f2bf(p);
            }
            sum += __shfl_xor(sum, 1);
            sum += __shfl_xor(sum, 2);
            sum += __shfl_xor(sum, 4);
            sum += __shfl_xor(sum, 8);
            lrun[r] = lrun[r] * al[r] + sum;
        }

        // rescale O, then O += P V   (per-wave Pb: same-wave dep, no barrier)
        const s8v pf0 = *(const s8v*)&Pb[w * 1152 + n16 * 72 + q4 * 8];
        const s8v pf1 = *(const s8v*)&Pb[w * 1152 + n16 * 72 + 32 + q4 * 8];
        #pragma unroll
        for (int t4 = 0; t4 < 4; t4++) {
            f4v o = O[t4];
            #pragma unroll
            for (int r = 0; r < 4; r++) o[r] *= al[r];
            const s8v v0 = *(const s8v*)&Vf[((t4 * 2 + 0) * 64 + lane) * 8];
            const s8v v1 = *(const s8v*)&Vf[((t4 * 2 + 1) * 64 + lane) * 8];
            o = __builtin_amdgcn_mfma_f32_16x16x32_bf16(pf0, v0, o, 0, 0, 0);
            o = __builtin_amdgcn_mfma_f32_16x16x32_bf16(pf1, v1, o, 0, 0, 0);
            O[t4] = o;
        }
    }

    // write UNNORMALIZED partial O (bf16) in (b, l, c) layout + per-row stats
    ushort* op = Opart + (size_t)half * PERBL + (size_t)b * L_SEQ * 512;
    #pragma unroll
    for (int r = 0; r < 4; r++) {
        const size_t base = (size_t)(rowbase + r) * 512 + h * 64;
        #pragma unroll
        for (int t4 = 0; t4 < 4; t4++)
            op[base + t4 * 16 + n16] = f2bf(O[t4][r]);
    }
    if (n16 == 0) {
        const size_t sb = (size_t)half * ROWS_TOT + (size_t)bh * L_SEQ;
        #pragma unroll
        for (int r = 0; r < 4; r++) {
            Mpart[sb + rowbase + r] = mrun[r];
            Lpart[sb + rowbase + r] = lrun[r];
        }
    }
}

// ==================================================================
// Merge key-half partials -> bf16 attnT (b, l, c). grid 1152, block 256.
__global__ __launch_bounds__(256) void combine_kernel(
    const ushort* __restrict__ O01, const float* __restrict__ Mp,
    const float* __restrict__ Lp, ushort* __restrict__ at)
{
    const int i   = blockIdx.x * 256 + threadIdx.x;  // 294912 chunks of 8
    const int c8  = i & 63;
    const int row = i >> 6;                          // b*L + l
    const int b   = row / L_SEQ;
    const int l   = row - b * L_SEQ;
    const int h   = c8 >> 3;
    const size_t s = (size_t)(b * NHEADS + h) * L_SEQ + l;
    const float m0 = Mp[s], m1 = Mp[ROWS_TOT + s];
    const float l0 = Lp[s], l1 = Lp[ROWS_TOT + s];
    const float M  = fmaxf(m0, m1);
    const float w0 = __expf(m0 - M);
    const float w1 = __expf(m1 - M);
    const float inv = 1.0f / (l0 * w0 + l1 * w1);
    const float f0 = w0 * inv;
    const float f1 = w1 * inv;
    const size_t o = (size_t)row * 512 + c8 * 8;
    const ushort4 a0 = *(const ushort4*)&O01[o];
    const ushort4 a1 = *(const ushort4*)&O01[o + 4];
    const ushort4 c0 = *(const ushort4*)&O01[PERBL + o];
    const ushort4 c1 = *(const ushort4*)&O01[PERBL + o + 4];
    ushort4 r0, r1;
    r0.x = f2bf(bf2f(a0.x) * f0 + bf2f(c0.x) * f1);
    r0.y = f2bf(bf2f(a0.y) * f0 + bf2f(c0.y) * f1);
    r0.z = f2bf(bf2f(a0.z) * f0 + bf2f(c0.z) * f1);
    r0.w = f2bf(bf2f(a0.w) * f0 + bf2f(c0.w) * f1);
    r1.x = f2bf(bf2f(a1.x) * f0 + bf2f(c1.x) * f1);
    r1.y = f2bf(bf2f(a1.y) * f0 + bf2f(c1.y) * f1);
    r1.z = f2bf(bf2f(a1.z) * f0 + bf2f(c1.z) * f1);
    r1.w = f2bf(bf2f(a1.w) * f0 + bf2f(c1.w) * f1);
    *(ushort4*)&at[o]     = r0;
    *(ushort4*)&at[o + 4] = r1;
}

// ==================================================================
// Output projection via bf16 MFMA + bias + residual. Same fragment scheme
// as qkv_mfma; epilogue float4 x-load / y-store (l contiguous).
// grid (36, 8, 2), block 256.
__global__ __launch_bounds__(256) void out_mfma(
    const ushort* __restrict__ at, const ushort* __restrict__ wb,
    const float* __restrict__ bo, const float* __restrict__ x,
    float* __restrict__ y)
{
    const int l0 = blockIdx.x * 64;
    const int o0 = blockIdx.y * 64;
    const int b  = blockIdx.z;
    const int t = threadIdx.x, w = t >> 6, lane = t & 63;
    const int n16 = lane & 15, q4 = lane >> 4;

    const ushort* A = at + ((size_t)b * L_SEQ + l0 + w * 16 + n16) * 512 + q4 * 8;
    const ushort* B = wb + (size_t)3 * 262144 + (size_t)(o0 + n16) * 512 + q4 * 8;

    f4v acc[4] = {{0.f,0.f,0.f,0.f},{0.f,0.f,0.f,0.f},{0.f,0.f,0.f,0.f},{0.f,0.f,0.f,0.f}};
    #pragma unroll
    for (int kc = 0; kc < 512; kc += 32) {
        const s8v a = *(const s8v*)&A[kc];
        #pragma unroll
        for (int t4 = 0; t4 < 4; t4++) {
            const s8v bf = *(const s8v*)&B[(size_t)(t4 * 16) * 512 + kc];
            acc[t4] = __builtin_amdgcn_mfma_f32_16x16x32_bf16(a, bf, acc[t4], 0, 0, 0);
        }
    }

    const int rowbase = l0 + w * 16 + q4 * 4;
    #pragma unroll
    for (int t4 = 0; t4 < 4; t4++) {
        const int o = o0 + t4 * 16 + n16;
        const float bi = bo[o];
        const size_t off = ((size_t)b * CDIM + o) * L_SEQ + rowbase;
        const float4 xv = *(const float4*)&x[off];
        float4 st;
        st.x = acc[t4][0] + bi + xv.x;
        st.y = acc[t4][1] + bi + xv.y;
        st.z = acc[t4][2] + bi + xv.z;
        st.w = acc[t4][3] + bi + xv.w;
        *(float4*)&y[off] = st;
    }
}

// ==================================================================
__global__ __launch_bounds__(256) void ln_kernel(
    float* __restrict__ y, const float* __restrict__ gamma,
    const float* __restrict__ beta)
{
    const int t  = threadIdx.x;
    const int pi = t & 63;
    const int g  = t >> 6;
    const int pos = blockIdx.x * 64 + pi;
    const int b = (pos >= L_SEQ) ? 1 : 0;
    const int l = pos - b * L_SEQ;
    float* col = y + (size_t)b * CDIM * L_SEQ + l;

    float s = 0.f, sq = 0.f;
    for (int c = g * 128; c < g * 128 + 128; c++) {
        const float v = col[(size_t)c * L_SEQ];
        s += v; sq += v * v;
    }
    __shared__ float S1[4][64];
    __shared__ float S2[4][64];
    S1[g][pi] = s; S2[g][pi] = sq;
    __syncthreads();
    if (g == 0) {
        s  = S1[0][pi] + S1[1][pi] + S1[2][pi] + S1[3][pi];
        sq = S2[0][pi] + S2[1][pi] + S2[2][pi] + S2[3][pi];
        const float mu = s * (1.0f / CDIM);
        const float var = sq * (1.0f / CDIM) - mu * mu;
        S1[0][pi] = mu;
        S2[0][pi] = rsqrtf(var + 1e-5f);
    }
    __syncthreads();
    const float mu = S1[0][pi];
    const float rs = S2[0][pi];
    for (int c = g * 128; c < g * 128 + 128; c++) {
        const float v = col[(size_t)c * L_SEQ];
        col[(size_t)c * L_SEQ] = (v - mu) * rs * gamma[c] + beta[c];
    }
}

// ==================================================================
extern "C" void kernel_launch(void* const* d_in, const int* in_sizes, int n_in,
                              void* d_out, int out_size, void* d_ws, size_t ws_size,
                              hipStream_t stream) {
    const float* x    = (const float*)d_in[0];
    const int* mask   = (const int*)d_in[1];
    const float* pos  = (const float*)d_in[2];
    const float* Wq   = (const float*)d_in[3];
    const float* bq   = (const float*)d_in[4];
    const float* Wk   = (const float*)d_in[5];
    const float* bk   = (const float*)d_in[6];
    const float* Wv   = (const float*)d_in[7];
    const float* bv   = (const float*)d_in[8];
    const float* Wo   = (const float*)d_in[9];
    const float* bo   = (const float*)d_in[10];
    const float* rel  = (const float*)d_in[11];
    const float* gam  = (const float*)d_in[12];
    const float* bet  = (const float*)d_in[13];

    // workspace layout (31.0 MB total, under proven-safe 33.6 MB):
    //   qw/kw/vw  3*PERBL ushort = 14.16 MB
    //   xtw         PERBL ushort =  4.72 MB  (reused as attnT)
    //   wbw     4*512*512 ushort =  2.10 MB
    //   Opart     2*PERBL ushort =  9.44 MB  (bf16 partials, 2 key-halves)
    //   Mpart/Lpart 4*ROWS_TOT f32 = 0.59 MB
    ushort* qw  = (ushort*)d_ws;
    ushort* kw  = qw + PERBL;
    ushort* vw  = kw + PERBL;
    ushort* xtw = vw + PERBL;
    ushort* wbw = xtw + PERBL;
    ushort* Opart = wbw + (size_t)4 * 512 * 512;
    float* Mpart = (float*)(Opart + 2 * PERBL);
    float* Lpart = Mpart + 2 * ROWS_TOT;
    ushort* attnT = xtw;                      // xt dead after qkv_mfma
    float* y = (float*)d_out;

    prep_w<<<dim3(1024), 256, 0, stream>>>(Wq, Wk, Wv, Wo, wbw);

    xpose<<<dim3(L_SEQ / 64, CDIM / 64, 2), 256, 0, stream>>>(x, pos, xtw);

    qkv_mfma<<<dim3(L_SEQ / 64, CDIM / 64, 6), 256, 0, stream>>>(
        xtw, wbw, bq, bk, bv, qw, kw, vw);

    flash_attn_mfma<<<dim3(1152), 256, 0, stream>>>(qw, kw, vw, mask, rel,
                                                    Opart, Mpart, Lpart);

    combine_kernel<<<dim3(1152), 256, 0, stream>>>(Opart, Mpart, Lpart, attnT);

    out_mfma<<<dim3(L_SEQ / 64, CDIM / 64, 2), 256, 0, stream>>>(
        attnT, wbw, bo, x, y);

    ln_kernel<<<(2 * L_SEQ) / 64, 256, 0, stream>>>(y, gam, bet);
}

// Round 6
// 396.196 us; speedup vs baseline: 1.4104x; 1.1446x over previous
//
#include <hip/hip_runtime.h>
#include <cstdint>

#define L_SEQ 2304
#define CDIM  512
#define NHEADS 8
#define HD    64
#define LL    ((size_t)L_SEQ * L_SEQ)
#define ROWS_TOT (16 * L_SEQ)            // 2 batches * 8 heads * L rows
#define PERBL ((size_t)2 * L_SEQ * 512)  // elems in one [2][L][512] plane

typedef short  s8v  __attribute__((ext_vector_type(8)));
typedef float  f4v  __attribute__((ext_vector_type(4)));

__device__ __forceinline__ ushort f2bf(float f) {
    union { float f; uint32_t u; } v; v.f = f;
    uint32_t u = v.u;
    uint32_t r = (u + 0x7FFFu + ((u >> 16) & 1u)) >> 16;
    return (ushort)r;
}

__device__ __forceinline__ float bf2f(ushort u) {
    union { uint32_t u; float f; } v; v.u = (uint32_t)u << 16;
    return v.f;
}

// ==================================================================
// Convert Wq,Wk,Wv,Wo (512x512 fp32, row-major (o,c)) to bf16.
// grid 1024, block 256 — one float4 per thread.
__global__ __launch_bounds__(256) void prep_w(
    const float* __restrict__ Wq, const float* __restrict__ Wk,
    const float* __restrict__ Wv, const float* __restrict__ Wo,
    ushort* __restrict__ wb)
{
    const int i   = blockIdx.x * 256 + threadIdx.x;  // 262144 float4 total
    const int mat = i >> 16;                         // 65536 float4 per mat
    const int j   = i & 65535;
    const float* src = (mat == 0) ? Wq : (mat == 1) ? Wk : (mat == 2) ? Wv : Wo;
    const float4 w = ((const float4*)src)[j];
    ushort4 o;
    o.x = f2bf(w.x); o.y = f2bf(w.y); o.z = f2bf(w.z); o.w = f2bf(w.w);
    ((ushort4*)(wb + (size_t)mat * 262144))[j] = o;
}

// ==================================================================
// XT[b][l][c] = bf16(x[b][c][l] + pos[c][l]).  64x64 LDS tile transpose.
// grid (36, 8, 2), block 256.
__global__ __launch_bounds__(256) void xpose(
    const float* __restrict__ x, const float* __restrict__ pos,
    ushort* __restrict__ xt)
{
    __shared__ ushort T[64][72];
    const int l0 = blockIdx.x * 64;
    const int c0 = blockIdx.y * 64;
    const int b  = blockIdx.z;
    const int t  = threadIdx.x;
    const int cc = t >> 2;
    const int l4 = (t & 3) * 16;
    const size_t off  = ((size_t)b * CDIM + c0 + cc) * L_SEQ + l0 + l4;
    const size_t poff = (size_t)(c0 + cc) * L_SEQ + l0 + l4;
    #pragma unroll
    for (int j4 = 0; j4 < 4; j4++) {
        const float4 xv = *(const float4*)&x[off + j4 * 4];
        const float4 pv = *(const float4*)&pos[poff + j4 * 4];
        T[cc][l4 + j4 * 4 + 0] = f2bf(xv.x + pv.x);
        T[cc][l4 + j4 * 4 + 1] = f2bf(xv.y + pv.y);
        T[cc][l4 + j4 * 4 + 2] = f2bf(xv.z + pv.z);
        T[cc][l4 + j4 * 4 + 3] = f2bf(xv.w + pv.w);
    }
    __syncthreads();
    const int lr = t >> 2;
    const int c4 = (t & 3) * 16;
    ushort o[16];
    #pragma unroll
    for (int j = 0; j < 16; j++) o[j] = T[c4 + j][lr];
    ushort* dst = &xt[((size_t)b * L_SEQ + l0 + lr) * 512 + c0 + c4];
    *(ushort4*)&dst[0]  = *(ushort4*)&o[0];
    *(ushort4*)&dst[4]  = *(ushort4*)&o[4];
    *(ushort4*)&dst[8]  = *(ushort4*)&o[8];
    *(ushort4*)&dst[12] = *(ushort4*)&o[12];
}

// ==================================================================
// QKV projection via bf16 MFMA with LDS-STAGED B (flash-style fragment-
// major staging: reg-stage global -> ds_write, conflict-free lane-
// contiguous ds_read_b128 fragments). Removes the 4x-redundant direct-L2
// B-fragment loads that made the round-5 version latency-bound.
// A (xt rows) stays direct-global: non-redundant, 1/5 of loads.
// grid (36, 8, 6), block 256 (4 waves, each 16 l-rows x 64 o).
__global__ __launch_bounds__(256) void qkv_mfma(
    const ushort* __restrict__ xt, const ushort* __restrict__ wb,
    const float* __restrict__ bq, const float* __restrict__ bk,
    const float* __restrict__ bv,
    ushort* __restrict__ q_t, ushort* __restrict__ k_t, ushort* __restrict__ v_t)
{
    __shared__ __align__(16) ushort Bs[1024 * 8];   // 16 KB, fragment-major
    const int l0  = blockIdx.x * 64;
    const int o0  = blockIdx.y * 64;     // == h*64
    const int b   = blockIdx.z / 3;
    const int mat = blockIdx.z % 3;
    const int t = threadIdx.x, w = t >> 6, lane = t & 63;
    const int n16 = lane & 15, q4 = lane >> 4;

    const ushort* A = xt + ((size_t)b * L_SEQ + l0 + w * 16 + n16) * 512 + q4 * 8;
    const ushort* W = wb + (size_t)mat * 262144;

    // staging decode for chunk c = t + 256*i: frag = c>>6 (ks = frag>>2,
    // t4 = frag&3), lane' = c&63. Chunk holds W[o0+t4*16+n16'][kb+ks*32+q4'*8..+8]
    int sRow[4], sCol[4];
    #pragma unroll
    for (int i = 0; i < 4; i++) {
        const int c  = t + 256 * i;
        const int fr = c >> 6, ln = c & 63;
        sRow[i] = o0 + (fr & 3) * 16 + (ln & 15);
        sCol[i] = (fr >> 2) * 32 + (ln >> 4) * 8;
    }

    f4v acc[4] = {{0.f,0.f,0.f,0.f},{0.f,0.f,0.f,0.f},{0.f,0.f,0.f,0.f},{0.f,0.f,0.f,0.f}};
    for (int kb = 0; kb < 512; kb += 128) {
        __syncthreads();   // WAR on Bs
        #pragma unroll
        for (int i = 0; i < 4; i++) {
            const int c = t + 256 * i;
            *(s8v*)&Bs[c * 8] = *(const s8v*)&W[(size_t)sRow[i] * 512 + kb + sCol[i]];
        }
        __syncthreads();
        #pragma unroll
        for (int ks = 0; ks < 4; ks++) {
            const s8v a = *(const s8v*)&A[kb + ks * 32];
            #pragma unroll
            for (int t4 = 0; t4 < 4; t4++) {
                const s8v bf = *(const s8v*)&Bs[((ks * 4 + t4) * 64 + lane) * 8];
                acc[t4] = __builtin_amdgcn_mfma_f32_16x16x32_bf16(a, bf, acc[t4], 0, 0, 0);
            }
        }
    }

    const float* bias = (mat == 0) ? bq : (mat == 1) ? bk : bv;
    const int h = o0 >> 6;
    const int rowbase = l0 + w * 16 + q4 * 4;

    if (mat < 2) {
        const float sc = (mat == 0) ? 0.125f : 1.0f;
        ushort* op = (mat == 0 ? q_t : k_t) + ((size_t)(b * NHEADS + h)) * L_SEQ * HD;
        #pragma unroll
        for (int t4 = 0; t4 < 4; t4++) {
            const float bi = bias[o0 + t4 * 16 + n16];
            #pragma unroll
            for (int r = 0; r < 4; r++)
                op[(size_t)(rowbase + r) * HD + t4 * 16 + n16] = f2bf((acc[t4][r] + bi) * sc);
        }
    } else {
        ushort* op = v_t + ((size_t)(b * NHEADS + h)) * HD * L_SEQ;
        #pragma unroll
        for (int t4 = 0; t4 < 4; t4++) {
            const float bi = bias[o0 + t4 * 16 + n16];
            ushort4 st;
            st.x = f2bf(acc[t4][0] + bi);
            st.y = f2bf(acc[t4][1] + bi);
            st.z = f2bf(acc[t4][2] + bi);
            st.w = f2bf(acc[t4][3] + bi);
            *(ushort4*)&op[(size_t)(t4 * 16 + n16) * L_SEQ + rowbase] = st;
        }
    }
}

// ==================================================================
// MFMA flash attention, split-K across blocks (round-2 staged structure,
// best measured). Partial O written bf16 in (b, l, c=h*64+d) layout.
// grid 1152 (1D, XCD-pinned head), block 256.
__global__ __launch_bounds__(256) void flash_attn_mfma(
    const ushort* __restrict__ q, const ushort* __restrict__ k,
    const ushort* __restrict__ vt, const int* __restrict__ mask,
    const float* __restrict__ rel_table, ushort* __restrict__ Opart,
    float* __restrict__ Mpart, float* __restrict__ Lpart)
{
    __shared__ __align__(16) ushort Kf[512 * 8];   // B-frags for S
    __shared__ __align__(16) ushort Vf[512 * 8];   // B-frags for PV
    __shared__ __align__(16) ushort Pb[4 * 16 * 72]; // per-wave P, row-major [16][72]
    __shared__ float rt[65];

    const int t    = threadIdx.x;
    const int id   = blockIdx.x;
    const int h    = id & 7;            // XCD-pinned head
    const int s2   = id >> 3;           // [0,144)
    const int b    = s2 & 1;            // adjacent slots share mask rows (L2 reuse)
    const int half = (s2 >> 1) & 1;     // key half
    const int qb   = s2 >> 2;           // [0,36)
    const int bh   = b * NHEADS + h;
    const int l0   = qb * 64;
    const int w    = t >> 6;
    const int lane = t & 63;
    const int n16  = lane & 15;
    const int q4   = lane >> 4;

    if (t < 65) rt[t] = rel_table[h * 65 + t];

    const ushort* qp = q  + (size_t)bh * L_SEQ * HD;
    const ushort* kp = k  + (size_t)bh * L_SEQ * HD;
    const ushort* vp = vt + (size_t)bh * HD * L_SEQ;
    const int*    mp = mask + (size_t)h * LL;

    // Q A-fragments: A[m=lane&15][k=quad*8+j], rows l0+w*16+n16
    const int qrow = l0 + w * 16 + n16;
    const s8v qA0 = *(const s8v*)&qp[(size_t)qrow * HD + q4 * 8];
    const s8v qA1 = *(const s8v*)&qp[(size_t)qrow * HD + 32 + q4 * 8];

    f4v O[4] = {{0.f,0.f,0.f,0.f},{0.f,0.f,0.f,0.f},{0.f,0.f,0.f,0.f},{0.f,0.f,0.f,0.f}};
    float mrun[4] = {-3e38f, -3e38f, -3e38f, -3e38f};
    float lrun[4] = {0.f, 0.f, 0.f, 0.f};

    // precompute this thread's two staging chunk decodes (c = t, t+256)
    int sT[2], sS[2], sQ[2], sN[2];
    #pragma unroll
    for (int cc = 0; cc < 2; cc++) {
        const int c = t + cc * 256;
        const int g = c >> 6;
        sT[cc] = g >> 1; sS[cc] = g & 1;
        sQ[cc] = (c >> 4) & 3; sN[cc] = c & 15;
    }

    const int rowbase = l0 + w * 16 + q4 * 4;   // +r gives the C-layout row
    const int kbase = half * 1152;

    for (int mt = 0; mt < 18; mt++) {
        const int mb = kbase + mt * 64;
        __syncthreads();   // WAR: previous tile's reads done before restage
        #pragma unroll
        for (int cc = 0; cc < 2; cc++) {
            const int c = t + cc * 256;
            const int key = sT[cc] * 16 + sN[cc];
            const int d0  = sS[cc] * 32 + sQ[cc] * 8;
            *(s8v*)&Kf[c * 8] = *(const s8v*)&kp[(size_t)(mb + key) * HD + d0];
            // V chunk: element j = V[mb + d0+j][sT*16+sN] = vt[(sT*16+sN)][mb+d0+j]
            const int dd = sT[cc] * 16 + sN[cc];
            *(s8v*)&Vf[c * 8] = *(const s8v*)&vp[(size_t)dd * L_SEQ + mb + d0];
        }
        __syncthreads();

        // mask loads (issue early; int32 per harness bool convention)
        int mreg[4][4];
        #pragma unroll
        for (int t4 = 0; t4 < 4; t4++)
            #pragma unroll
            for (int r = 0; r < 4; r++)
                mreg[t4][r] = mp[(size_t)(rowbase + r) * L_SEQ + mb + t4 * 16 + n16];

        // S = Q K^T  (C layout: col=lane&15 -> key t4*16+n16, row=q4*4+r)
        f4v S[4];
        #pragma unroll
        for (int t4 = 0; t4 < 4; t4++) {
            const s8v b0 = *(const s8v*)&Kf[((t4 * 2 + 0) * 64 + lane) * 8];
            const s8v b1 = *(const s8v*)&Kf[((t4 * 2 + 1) * 64 + lane) * 8];
            f4v acc = {0.f, 0.f, 0.f, 0.f};
            acc = __builtin_amdgcn_mfma_f32_16x16x32_bf16(qA0, b0, acc, 0, 0, 0);
            acc = __builtin_amdgcn_mfma_f32_16x16x32_bf16(qA1, b1, acc, 0, 0, 0);
            S[t4] = acc;
        }

        // relative positional bias (then mask -> exactly -1e9, matching ref order)
        #pragma unroll
        for (int t4 = 0; t4 < 4; t4++) {
            const int A = (l0 + w * 16) - (mb + t4 * 16);
            if (A >= 47) {
                const float bu = rt[64];
                #pragma unroll
                for (int r = 0; r < 4; r++) S[t4][r] += bu;
            } else if (A <= -47) {
                const float bu = rt[0];
                #pragma unroll
                for (int r = 0; r < 4; r++) S[t4][r] += bu;
            } else {
                #pragma unroll
                for (int r = 0; r < 4; r++) {
                    int dix = A + q4 * 4 + r - n16;
                    dix = min(max(dix, -32), 32) + 32;
                    S[t4][r] += rt[dix];
                }
            }
            #pragma unroll
            for (int r = 0; r < 4; r++)
                if (mreg[t4][r] == 0) S[t4][r] = -1e9f;
        }

        // online softmax per row (row stats replicated over 16 lanes of quad)
        float mx[4];
        #pragma unroll
        for (int r = 0; r < 4; r++) {
            float m0 = fmaxf(fmaxf(S[0][r], S[1][r]), fmaxf(S[2][r], S[3][r]));
            m0 = fmaxf(m0, __shfl_xor(m0, 1));
            m0 = fmaxf(m0, __shfl_xor(m0, 2));
            m0 = fmaxf(m0, __shfl_xor(m0, 4));
            m0 = fmaxf(m0, __shfl_xor(m0, 8));
            mx[r] = m0;
        }
        float al[4];
        #pragma unroll
        for (int r = 0; r < 4; r++) {
            const float mn = fmaxf(mrun[r], mx[r]);
            al[r] = __expf(mrun[r] - mn);
            mrun[r] = mn;
            float sum = 0.f;
            #pragma unroll
            for (int t4 = 0; t4 < 4; t4++) {
                const float p = __expf(S[t4][r] - mn);
                S[t4][r] = p;
                sum += p;
                Pb[w * 1152 + (q4 * 4 + r) * 72 + t4 * 16 + n16] = f2bf(p);
            }
            sum += __shfl_xor(sum, 1);
            sum += __shfl_xor(sum, 2);
            sum += __shfl_xor(sum, 4);
            sum += __shfl_xor(sum, 8);
            lrun[r] = lrun[r] * al[r] + sum;
        }

        // rescale O, then O += P V   (per-wave Pb: same-wave dep, no barrier)
        const s8v pf0 = *(const s8v*)&Pb[w * 1152 + n16 * 72 + q4 * 8];
        const s8v pf1 = *(const s8v*)&Pb[w * 1152 + n16 * 72 + 32 + q4 * 8];
        #pragma unroll
        for (int t4 = 0; t4 < 4; t4++) {
            f4v o = O[t4];
            #pragma unroll
            for (int r = 0; r < 4; r++) o[r] *= al[r];
            const s8v v0 = *(const s8v*)&Vf[((t4 * 2 + 0) * 64 + lane) * 8];
            const s8v v1 = *(const s8v*)&Vf[((t4 * 2 + 1) * 64 + lane) * 8];
            o = __builtin_amdgcn_mfma_f32_16x16x32_bf16(pf0, v0, o, 0, 0, 0);
            o = __builtin_amdgcn_mfma_f32_16x16x32_bf16(pf1, v1, o, 0, 0, 0);
            O[t4] = o;
        }
    }

    // write UNNORMALIZED partial O (bf16) in (b, l, c) layout + per-row stats
    ushort* op = Opart + (size_t)half * PERBL + (size_t)b * L_SEQ * 512;
    #pragma unroll
    for (int r = 0; r < 4; r++) {
        const size_t base = (size_t)(rowbase + r) * 512 + h * 64;
        #pragma unroll
        for (int t4 = 0; t4 < 4; t4++)
            op[base + t4 * 16 + n16] = f2bf(O[t4][r]);
    }
    if (n16 == 0) {
        const size_t sb = (size_t)half * ROWS_TOT + (size_t)bh * L_SEQ;
        #pragma unroll
        for (int r = 0; r < 4; r++) {
            Mpart[sb + rowbase + r] = mrun[r];
            Lpart[sb + rowbase + r] = lrun[r];
        }
    }
}

// ==================================================================
// Merge key-half partials -> bf16 attnT (b, l, c). grid 1152, block 256.
__global__ __launch_bounds__(256) void combine_kernel(
    const ushort* __restrict__ O01, const float* __restrict__ Mp,
    const float* __restrict__ Lp, ushort* __restrict__ at)
{
    const int i   = blockIdx.x * 256 + threadIdx.x;  // 294912 chunks of 8
    const int c8  = i & 63;
    const int row = i >> 6;                          // b*L + l
    const int b   = row / L_SEQ;
    const int l   = row - b * L_SEQ;
    const int h   = c8 >> 3;
    const size_t s = (size_t)(b * NHEADS + h) * L_SEQ + l;
    const float m0 = Mp[s], m1 = Mp[ROWS_TOT + s];
    const float l0 = Lp[s], l1 = Lp[ROWS_TOT + s];
    const float M  = fmaxf(m0, m1);
    const float w0 = __expf(m0 - M);
    const float w1 = __expf(m1 - M);
    const float inv = 1.0f / (l0 * w0 + l1 * w1);
    const float f0 = w0 * inv;
    const float f1 = w1 * inv;
    const size_t o = (size_t)row * 512 + c8 * 8;
    const ushort4 a0 = *(const ushort4*)&O01[o];
    const ushort4 a1 = *(const ushort4*)&O01[o + 4];
    const ushort4 c0 = *(const ushort4*)&O01[PERBL + o];
    const ushort4 c1 = *(const ushort4*)&O01[PERBL + o + 4];
    ushort4 r0, r1;
    r0.x = f2bf(bf2f(a0.x) * f0 + bf2f(c0.x) * f1);
    r0.y = f2bf(bf2f(a0.y) * f0 + bf2f(c0.y) * f1);
    r0.z = f2bf(bf2f(a0.z) * f0 + bf2f(c0.z) * f1);
    r0.w = f2bf(bf2f(a0.w) * f0 + bf2f(c0.w) * f1);
    r1.x = f2bf(bf2f(a1.x) * f0 + bf2f(c1.x) * f1);
    r1.y = f2bf(bf2f(a1.y) * f0 + bf2f(c1.y) * f1);
    r1.z = f2bf(bf2f(a1.z) * f0 + bf2f(c1.z) * f1);
    r1.w = f2bf(bf2f(a1.w) * f0 + bf2f(c1.w) * f1);
    *(ushort4*)&at[o]     = r0;
    *(ushort4*)&at[o + 4] = r1;
}

// ==================================================================
// Output projection via bf16 MFMA with LDS-staged B + bias + residual.
// grid (36, 8, 2), block 256.
__global__ __launch_bounds__(256) void out_mfma(
    const ushort* __restrict__ at, const ushort* __restrict__ wb,
    const float* __restrict__ bo, const float* __restrict__ x,
    float* __restrict__ y)
{
    __shared__ __align__(16) ushort Bs[1024 * 8];   // 16 KB, fragment-major
    const int l0 = blockIdx.x * 64;
    const int o0 = blockIdx.y * 64;
    const int b  = blockIdx.z;
    const int t = threadIdx.x, w = t >> 6, lane = t & 63;
    const int n16 = lane & 15, q4 = lane >> 4;

    const ushort* A = at + ((size_t)b * L_SEQ + l0 + w * 16 + n16) * 512 + q4 * 8;
    const ushort* W = wb + (size_t)3 * 262144;

    int sRow[4], sCol[4];
    #pragma unroll
    for (int i = 0; i < 4; i++) {
        const int c  = t + 256 * i;
        const int fr = c >> 6, ln = c & 63;
        sRow[i] = o0 + (fr & 3) * 16 + (ln & 15);
        sCol[i] = (fr >> 2) * 32 + (ln >> 4) * 8;
    }

    f4v acc[4] = {{0.f,0.f,0.f,0.f},{0.f,0.f,0.f,0.f},{0.f,0.f,0.f,0.f},{0.f,0.f,0.f,0.f}};
    for (int kb = 0; kb < 512; kb += 128) {
        __syncthreads();
        #pragma unroll
        for (int i = 0; i < 4; i++) {
            const int c = t + 256 * i;
            *(s8v*)&Bs[c * 8] = *(const s8v*)&W[(size_t)sRow[i] * 512 + kb + sCol[i]];
        }
        __syncthreads();
        #pragma unroll
        for (int ks = 0; ks < 4; ks++) {
            const s8v a = *(const s8v*)&A[kb + ks * 32];
            #pragma unroll
            for (int t4 = 0; t4 < 4; t4++) {
                const s8v bf = *(const s8v*)&Bs[((ks * 4 + t4) * 64 + lane) * 8];
                acc[t4] = __builtin_amdgcn_mfma_f32_16x16x32_bf16(a, bf, acc[t4], 0, 0, 0);
            }
        }
    }

    const int rowbase = l0 + w * 16 + q4 * 4;
    #pragma unroll
    for (int t4 = 0; t4 < 4; t4++) {
        const int o = o0 + t4 * 16 + n16;
        const float bi = bo[o];
        const size_t off = ((size_t)b * CDIM + o) * L_SEQ + rowbase;
        const float4 xv = *(const float4*)&x[off];
        float4 st;
        st.x = acc[t4][0] + bi + xv.x;
        st.y = acc[t4][1] + bi + xv.y;
        st.z = acc[t4][2] + bi + xv.z;
        st.w = acc[t4][3] + bi + xv.w;
        *(float4*)&y[off] = st;
    }
}

// ==================================================================
// LayerNorm over channels. 288 blocks (was 72 — 0.28 blocks/CU was a
// structural parallelism bug). 16 positions/block, 16 threads/position.
__global__ __launch_bounds__(256) void ln_kernel(
    float* __restrict__ y, const float* __restrict__ gamma,
    const float* __restrict__ beta)
{
    const int t = threadIdx.x;
    const int p = t & 15;         // position within block
    const int g = t >> 4;         // channel group: 16 groups x 32 ch
    const int pos = blockIdx.x * 16 + p;
    const int b = (pos >= L_SEQ) ? 1 : 0;
    const int l = pos - b * L_SEQ;
    float* col = y + (size_t)b * CDIM * L_SEQ + l;

    float s = 0.f, sq = 0.f;
    for (int c = g * 32; c < g * 32 + 32; c++) {
        const float v = col[(size_t)c * L_SEQ];
        s += v; sq += v * v;
    }
    __shared__ float S1[16][16];
    __shared__ float S2[16][16];
    S1[g][p] = s; S2[g][p] = sq;
    __syncthreads();
    if (t < 16) {
        float ss = 0.f, qq = 0.f;
        #pragma unroll
        for (int gg = 0; gg < 16; gg++) { ss += S1[gg][t]; qq += S2[gg][t]; }
        const float mu = ss * (1.0f / CDIM);
        const float var = qq * (1.0f / CDIM) - mu * mu;
        S1[0][t] = mu;
        S2[0][t] = rsqrtf(var + 1e-5f);
    }
    __syncthreads();
    const float mu = S1[0][p];
    const float rs = S2[0][p];
    for (int c = g * 32; c < g * 32 + 32; c++) {
        const float v = col[(size_t)c * L_SEQ];
        col[(size_t)c * L_SEQ] = (v - mu) * rs * gamma[c] + beta[c];
    }
}

// ==================================================================
extern "C" void kernel_launch(void* const* d_in, const int* in_sizes, int n_in,
                              void* d_out, int out_size, void* d_ws, size_t ws_size,
                              hipStream_t stream) {
    const float* x    = (const float*)d_in[0];
    const int* mask   = (const int*)d_in[1];
    const float* pos  = (const float*)d_in[2];
    const float* Wq   = (const float*)d_in[3];
    const float* bq   = (const float*)d_in[4];
    const float* Wk   = (const float*)d_in[5];
    const float* bk   = (const float*)d_in[6];
    const float* Wv   = (const float*)d_in[7];
    const float* bv   = (const float*)d_in[8];
    const float* Wo   = (const float*)d_in[9];
    const float* bo   = (const float*)d_in[10];
    const float* rel  = (const float*)d_in[11];
    const float* gam  = (const float*)d_in[12];
    const float* bet  = (const float*)d_in[13];

    // workspace layout (31.0 MB total, proven safe):
    ushort* qw  = (ushort*)d_ws;
    ushort* kw  = qw + PERBL;
    ushort* vw  = kw + PERBL;
    ushort* xtw = vw + PERBL;
    ushort* wbw = xtw + PERBL;
    ushort* Opart = wbw + (size_t)4 * 512 * 512;
    float* Mpart = (float*)(Opart + 2 * PERBL);
    float* Lpart = Mpart + 2 * ROWS_TOT;
    ushort* attnT = xtw;                      // xt dead after qkv_mfma
    float* y = (float*)d_out;

    prep_w<<<dim3(1024), 256, 0, stream>>>(Wq, Wk, Wv, Wo, wbw);

    xpose<<<dim3(L_SEQ / 64, CDIM / 64, 2), 256, 0, stream>>>(x, pos, xtw);

    qkv_mfma<<<dim3(L_SEQ / 64, CDIM / 64, 6), 256, 0, stream>>>(
        xtw, wbw, bq, bk, bv, qw, kw, vw);

    flash_attn_mfma<<<dim3(1152), 256, 0, stream>>>(qw, kw, vw, mask, rel,
                                                    Opart, Mpart, Lpart);

    combine_kernel<<<dim3(1152), 256, 0, stream>>>(Opart, Mpart, Lpart, attnT);

    out_mfma<<<dim3(L_SEQ / 64, CDIM / 64, 2), 256, 0, stream>>>(
        attnT, wbw, bo, x, y);

    ln_kernel<<<(2 * L_SEQ) / 16, 256, 0, stream>>>(y, gam, bet);
}

// Round 7
// 394.950 us; speedup vs baseline: 1.4148x; 1.0032x over previous
//
#include <hip/hip_runtime.h>
#include <cstdint>

#define L_SEQ 2304
#define CDIM  512
#define NHEADS 8
#define HD    64
#define LL    ((size_t)L_SEQ * L_SEQ)
#define ROWS_TOT (16 * L_SEQ)            // 2 batches * 8 heads * L rows
#define PERBL ((size_t)2 * L_SEQ * 512)  // elems in one [2][L][512] plane

typedef short  s8v  __attribute__((ext_vector_type(8)));
typedef float  f4v  __attribute__((ext_vector_type(4)));

__device__ __forceinline__ ushort f2bf(float f) {
    union { float f; uint32_t u; } v; v.f = f;
    uint32_t u = v.u;
    uint32_t r = (u + 0x7FFFu + ((u >> 16) & 1u)) >> 16;
    return (ushort)r;
}

__device__ __forceinline__ float bf2f(ushort u) {
    union { uint32_t u; float f; } v; v.u = (uint32_t)u << 16;
    return v.f;
}

// ==================================================================
// Convert Wq,Wk,Wv,Wo (512x512 fp32, row-major (o,c)) to bf16.
// grid 1024, block 256 — one float4 per thread.
__global__ __launch_bounds__(256) void prep_w(
    const float* __restrict__ Wq, const float* __restrict__ Wk,
    const float* __restrict__ Wv, const float* __restrict__ Wo,
    ushort* __restrict__ wb)
{
    const int i   = blockIdx.x * 256 + threadIdx.x;  // 262144 float4 total
    const int mat = i >> 16;                         // 65536 float4 per mat
    const int j   = i & 65535;
    const float* src = (mat == 0) ? Wq : (mat == 1) ? Wk : (mat == 2) ? Wv : Wo;
    const float4 w = ((const float4*)src)[j];
    ushort4 o;
    o.x = f2bf(w.x); o.y = f2bf(w.y); o.z = f2bf(w.z); o.w = f2bf(w.w);
    ((ushort4*)(wb + (size_t)mat * 262144))[j] = o;
}

// ==================================================================
// XT[b][l][c] = bf16(x[b][c][l] + pos[c][l]).  64x64 LDS tile transpose.
// grid (36, 8, 2), block 256.
__global__ __launch_bounds__(256) void xpose(
    const float* __restrict__ x, const float* __restrict__ pos,
    ushort* __restrict__ xt)
{
    __shared__ ushort T[64][72];
    const int l0 = blockIdx.x * 64;
    const int c0 = blockIdx.y * 64;
    const int b  = blockIdx.z;
    const int t  = threadIdx.x;
    const int cc = t >> 2;
    const int l4 = (t & 3) * 16;
    const size_t off  = ((size_t)b * CDIM + c0 + cc) * L_SEQ + l0 + l4;
    const size_t poff = (size_t)(c0 + cc) * L_SEQ + l0 + l4;
    #pragma unroll
    for (int j4 = 0; j4 < 4; j4++) {
        const float4 xv = *(const float4*)&x[off + j4 * 4];
        const float4 pv = *(const float4*)&pos[poff + j4 * 4];
        T[cc][l4 + j4 * 4 + 0] = f2bf(xv.x + pv.x);
        T[cc][l4 + j4 * 4 + 1] = f2bf(xv.y + pv.y);
        T[cc][l4 + j4 * 4 + 2] = f2bf(xv.z + pv.z);
        T[cc][l4 + j4 * 4 + 3] = f2bf(xv.w + pv.w);
    }
    __syncthreads();
    const int lr = t >> 2;
    const int c4 = (t & 3) * 16;
    ushort o[16];
    #pragma unroll
    for (int j = 0; j < 16; j++) o[j] = T[c4 + j][lr];
    ushort* dst = &xt[((size_t)b * L_SEQ + l0 + lr) * 512 + c0 + c4];
    *(ushort4*)&dst[0]  = *(ushort4*)&o[0];
    *(ushort4*)&dst[4]  = *(ushort4*)&o[4];
    *(ushort4*)&dst[8]  = *(ushort4*)&o[8];
    *(ushort4*)&dst[12] = *(ushort4*)&o[12];
}

// ==================================================================
// QKV projection via bf16 MFMA. All 3 mats in one block (A read once,
// not 3x), A-fragments ENTIRELY in registers upfront (no in-loop global
// loads), B double-buffered through registers: next chunk's global loads
// issue right after the current ds_write, hiding L2 latency under the
// 48 MFMAs per chunk. LDS 48 KB (3 mats x 16 KB fragment-major).
// grid (36, 8, 2), block 256 (4 waves, each 16 l-rows x 64 o x 3 mats).
__global__ __launch_bounds__(256) void qkv_mfma(
    const ushort* __restrict__ xt, const ushort* __restrict__ wb,
    const float* __restrict__ bq, const float* __restrict__ bk,
    const float* __restrict__ bv,
    ushort* __restrict__ q_t, ushort* __restrict__ k_t, ushort* __restrict__ v_t)
{
    __shared__ __align__(16) ushort Bs[3][1024 * 8];   // 48 KB
    const int l0  = blockIdx.x * 64;
    const int o0  = blockIdx.y * 64;     // == h*64
    const int b   = blockIdx.z;
    const int t = threadIdx.x, w = t >> 6, lane = t & 63;
    const int n16 = lane & 15, q4 = lane >> 4;

    const ushort* A = xt + ((size_t)b * L_SEQ + l0 + w * 16 + n16) * 512 + q4 * 8;

    // all 16 A-fragments in registers before the k-loop (32 VGPR)
    s8v areg[16];
    #pragma unroll
    for (int i = 0; i < 16; i++) areg[i] = *(const s8v*)&A[i * 32];

    // staging decode for chunk c = t + 256*i
    int sOff[4];
    #pragma unroll
    for (int i = 0; i < 4; i++) {
        const int c  = t + 256 * i;
        const int fr = c >> 6, ln = c & 63;
        sOff[i] = (o0 + (fr & 3) * 16 + (ln & 15)) * 512 + (fr >> 2) * 32 + (ln >> 4) * 8;
    }

    // preload chunk kb=0 into registers
    s8v breg[3][4];
    #pragma unroll
    for (int m = 0; m < 3; m++)
        #pragma unroll
        for (int i = 0; i < 4; i++)
            breg[m][i] = *(const s8v*)&wb[(size_t)m * 262144 + sOff[i]];

    f4v acc[3][4] = {};
    for (int kb = 0; kb < 512; kb += 128) {
        __syncthreads();   // WAR on Bs
        #pragma unroll
        for (int m = 0; m < 3; m++)
            #pragma unroll
            for (int i = 0; i < 4; i++)
                *(s8v*)&Bs[m][(t + 256 * i) * 8] = breg[m][i];
        __syncthreads();
        if (kb < 384) {   // issue next chunk's loads; consumed at next ds_write
            #pragma unroll
            for (int m = 0; m < 3; m++)
                #pragma unroll
                for (int i = 0; i < 4; i++)
                    breg[m][i] = *(const s8v*)&wb[(size_t)m * 262144 + sOff[i] + kb + 128];
        }
        #pragma unroll
        for (int ks = 0; ks < 4; ks++) {
            const s8v a = areg[(kb >> 5) + ks];
            #pragma unroll
            for (int m = 0; m < 3; m++)
                #pragma unroll
                for (int t4 = 0; t4 < 4; t4++) {
                    const s8v bf = *(const s8v*)&Bs[m][((ks * 4 + t4) * 64 + lane) * 8];
                    acc[m][t4] = __builtin_amdgcn_mfma_f32_16x16x32_bf16(a, bf, acc[m][t4], 0, 0, 0);
                }
        }
    }

    const int h = o0 >> 6;
    const int rowbase = l0 + w * 16 + q4 * 4;

    // q (mat 0, scaled) and k (mat 1): row-major (b,h,l,d)
    #pragma unroll
    for (int m = 0; m < 2; m++) {
        const float* bias = (m == 0) ? bq : bk;
        const float sc = (m == 0) ? 0.125f : 1.0f;
        ushort* op = (m == 0 ? q_t : k_t) + ((size_t)(b * NHEADS + h)) * L_SEQ * HD;
        #pragma unroll
        for (int t4 = 0; t4 < 4; t4++) {
            const float bi = bias[o0 + t4 * 16 + n16];
            #pragma unroll
            for (int r = 0; r < 4; r++)
                op[(size_t)(rowbase + r) * HD + t4 * 16 + n16] = f2bf((acc[m][t4][r] + bi) * sc);
        }
    }
    // v (mat 2): transposed (b,h,d,l)
    {
        ushort* op = v_t + ((size_t)(b * NHEADS + h)) * HD * L_SEQ;
        #pragma unroll
        for (int t4 = 0; t4 < 4; t4++) {
            const float bi = bv[o0 + t4 * 16 + n16];
            ushort4 st;
            st.x = f2bf(acc[2][t4][0] + bi);
            st.y = f2bf(acc[2][t4][1] + bi);
            st.z = f2bf(acc[2][t4][2] + bi);
            st.w = f2bf(acc[2][t4][3] + bi);
            *(ushort4*)&op[(size_t)(t4 * 16 + n16) * L_SEQ + rowbase] = st;
        }
    }
}

// ==================================================================
// MFMA flash attention, split-K across blocks (round-2 staged structure,
// best measured). Partial O written bf16 in (b, l, c=h*64+d) layout.
// grid 1152 (1D, XCD-pinned head), block 256.
__global__ __launch_bounds__(256) void flash_attn_mfma(
    const ushort* __restrict__ q, const ushort* __restrict__ k,
    const ushort* __restrict__ vt, const int* __restrict__ mask,
    const float* __restrict__ rel_table, ushort* __restrict__ Opart,
    float* __restrict__ Mpart, float* __restrict__ Lpart)
{
    __shared__ __align__(16) ushort Kf[512 * 8];   // B-frags for S
    __shared__ __align__(16) ushort Vf[512 * 8];   // B-frags for PV
    __shared__ __align__(16) ushort Pb[4 * 16 * 72]; // per-wave P, row-major [16][72]
    __shared__ float rt[65];

    const int t    = threadIdx.x;
    const int id   = blockIdx.x;
    const int h    = id & 7;            // XCD-pinned head
    const int s2   = id >> 3;           // [0,144)
    const int b    = s2 & 1;            // adjacent slots share mask rows (L2 reuse)
    const int half = (s2 >> 1) & 1;     // key half
    const int qb   = s2 >> 2;           // [0,36)
    const int bh   = b * NHEADS + h;
    const int l0   = qb * 64;
    const int w    = t >> 6;
    const int lane = t & 63;
    const int n16  = lane & 15;
    const int q4   = lane >> 4;

    if (t < 65) rt[t] = rel_table[h * 65 + t];

    const ushort* qp = q  + (size_t)bh * L_SEQ * HD;
    const ushort* kp = k  + (size_t)bh * L_SEQ * HD;
    const ushort* vp = vt + (size_t)bh * HD * L_SEQ;
    const int*    mp = mask + (size_t)h * LL;

    // Q A-fragments: A[m=lane&15][k=quad*8+j], rows l0+w*16+n16
    const int qrow = l0 + w * 16 + n16;
    const s8v qA0 = *(const s8v*)&qp[(size_t)qrow * HD + q4 * 8];
    const s8v qA1 = *(const s8v*)&qp[(size_t)qrow * HD + 32 + q4 * 8];

    f4v O[4] = {{0.f,0.f,0.f,0.f},{0.f,0.f,0.f,0.f},{0.f,0.f,0.f,0.f},{0.f,0.f,0.f,0.f}};
    float mrun[4] = {-3e38f, -3e38f, -3e38f, -3e38f};
    float lrun[4] = {0.f, 0.f, 0.f, 0.f};

    // precompute this thread's two staging chunk decodes (c = t, t+256)
    int sT[2], sS[2], sQ[2], sN[2];
    #pragma unroll
    for (int cc = 0; cc < 2; cc++) {
        const int c = t + cc * 256;
        const int g = c >> 6;
        sT[cc] = g >> 1; sS[cc] = g & 1;
        sQ[cc] = (c >> 4) & 3; sN[cc] = c & 15;
    }

    const int rowbase = l0 + w * 16 + q4 * 4;   // +r gives the C-layout row
    const int kbase = half * 1152;

    for (int mt = 0; mt < 18; mt++) {
        const int mb = kbase + mt * 64;
        __syncthreads();   // WAR: previous tile's reads done before restage
        #pragma unroll
        for (int cc = 0; cc < 2; cc++) {
            const int c = t + cc * 256;
            const int key = sT[cc] * 16 + sN[cc];
            const int d0  = sS[cc] * 32 + sQ[cc] * 8;
            *(s8v*)&Kf[c * 8] = *(const s8v*)&kp[(size_t)(mb + key) * HD + d0];
            // V chunk: element j = V[mb + d0+j][sT*16+sN] = vt[(sT*16+sN)][mb+d0+j]
            const int dd = sT[cc] * 16 + sN[cc];
            *(s8v*)&Vf[c * 8] = *(const s8v*)&vp[(size_t)dd * L_SEQ + mb + d0];
        }
        __syncthreads();

        // mask loads (issue early; int32 per harness bool convention)
        int mreg[4][4];
        #pragma unroll
        for (int t4 = 0; t4 < 4; t4++)
            #pragma unroll
            for (int r = 0; r < 4; r++)
                mreg[t4][r] = mp[(size_t)(rowbase + r) * L_SEQ + mb + t4 * 16 + n16];

        // S = Q K^T  (C layout: col=lane&15 -> key t4*16+n16, row=q4*4+r)
        f4v S[4];
        #pragma unroll
        for (int t4 = 0; t4 < 4; t4++) {
            const s8v b0 = *(const s8v*)&Kf[((t4 * 2 + 0) * 64 + lane) * 8];
            const s8v b1 = *(const s8v*)&Kf[((t4 * 2 + 1) * 64 + lane) * 8];
            f4v acc = {0.f, 0.f, 0.f, 0.f};
            acc = __builtin_amdgcn_mfma_f32_16x16x32_bf16(qA0, b0, acc, 0, 0, 0);
            acc = __builtin_amdgcn_mfma_f32_16x16x32_bf16(qA1, b1, acc, 0, 0, 0);
            S[t4] = acc;
        }

        // relative positional bias (then mask -> exactly -1e9, matching ref order)
        #pragma unroll
        for (int t4 = 0; t4 < 4; t4++) {
            const int A = (l0 + w * 16) - (mb + t4 * 16);
            if (A >= 47) {
                const float bu = rt[64];
                #pragma unroll
                for (int r = 0; r < 4; r++) S[t4][r] += bu;
            } else if (A <= -47) {
                const float bu = rt[0];
                #pragma unroll
                for (int r = 0; r < 4; r++) S[t4][r] += bu;
            } else {
                #pragma unroll
                for (int r = 0; r < 4; r++) {
                    int dix = A + q4 * 4 + r - n16;
                    dix = min(max(dix, -32), 32) + 32;
                    S[t4][r] += rt[dix];
                }
            }
            #pragma unroll
            for (int r = 0; r < 4; r++)
                if (mreg[t4][r] == 0) S[t4][r] = -1e9f;
        }

        // online softmax per row (row stats replicated over 16 lanes of quad)
        float mx[4];
        #pragma unroll
        for (int r = 0; r < 4; r++) {
            float m0 = fmaxf(fmaxf(S[0][r], S[1][r]), fmaxf(S[2][r], S[3][r]));
            m0 = fmaxf(m0, __shfl_xor(m0, 1));
            m0 = fmaxf(m0, __shfl_xor(m0, 2));
            m0 = fmaxf(m0, __shfl_xor(m0, 4));
            m0 = fmaxf(m0, __shfl_xor(m0, 8));
            mx[r] = m0;
        }
        float al[4];
        #pragma unroll
        for (int r = 0; r < 4; r++) {
            const float mn = fmaxf(mrun[r], mx[r]);
            al[r] = __expf(mrun[r] - mn);
            mrun[r] = mn;
            float sum = 0.f;
            #pragma unroll
            for (int t4 = 0; t4 < 4; t4++) {
                const float p = __expf(S[t4][r] - mn);
                S[t4][r] = p;
                sum += p;
                Pb[w * 1152 + (q4 * 4 + r) * 72 + t4 * 16 + n16] = f2bf(p);
            }
            sum += __shfl_xor(sum, 1);
            sum += __shfl_xor(sum, 2);
            sum += __shfl_xor(sum, 4);
            sum += __shfl_xor(sum, 8);
            lrun[r] = lrun[r] * al[r] + sum;
        }

        // rescale O, then O += P V   (per-wave Pb: same-wave dep, no barrier)
        const s8v pf0 = *(const s8v*)&Pb[w * 1152 + n16 * 72 + q4 * 8];
        const s8v pf1 = *(const s8v*)&Pb[w * 1152 + n16 * 72 + 32 + q4 * 8];
        #pragma unroll
        for (int t4 = 0; t4 < 4; t4++) {
            f4v o = O[t4];
            #pragma unroll
            for (int r = 0; r < 4; r++) o[r] *= al[r];
            const s8v v0 = *(const s8v*)&Vf[((t4 * 2 + 0) * 64 + lane) * 8];
            const s8v v1 = *(const s8v*)&Vf[((t4 * 2 + 1) * 64 + lane) * 8];
            o = __builtin_amdgcn_mfma_f32_16x16x32_bf16(pf0, v0, o, 0, 0, 0);
            o = __builtin_amdgcn_mfma_f32_16x16x32_bf16(pf1, v1, o, 0, 0, 0);
            O[t4] = o;
        }
    }

    // write UNNORMALIZED partial O (bf16) in (b, l, c) layout + per-row stats
    ushort* op = Opart + (size_t)half * PERBL + (size_t)b * L_SEQ * 512;
    #pragma unroll
    for (int r = 0; r < 4; r++) {
        const size_t base = (size_t)(rowbase + r) * 512 + h * 64;
        #pragma unroll
        for (int t4 = 0; t4 < 4; t4++)
            op[base + t4 * 16 + n16] = f2bf(O[t4][r]);
    }
    if (n16 == 0) {
        const size_t sb = (size_t)half * ROWS_TOT + (size_t)bh * L_SEQ;
        #pragma unroll
        for (int r = 0; r < 4; r++) {
            Mpart[sb + rowbase + r] = mrun[r];
            Lpart[sb + rowbase + r] = lrun[r];
        }
    }
}

// ==================================================================
// Merge key-half partials -> bf16 attnT (b, l, c). grid 1152, block 256.
__global__ __launch_bounds__(256) void combine_kernel(
    const ushort* __restrict__ O01, const float* __restrict__ Mp,
    const float* __restrict__ Lp, ushort* __restrict__ at)
{
    const int i   = blockIdx.x * 256 + threadIdx.x;  // 294912 chunks of 8
    const int c8  = i & 63;
    const int row = i >> 6;                          // b*L + l
    const int b   = row / L_SEQ;
    const int l   = row - b * L_SEQ;
    const int h   = c8 >> 3;
    const size_t s = (size_t)(b * NHEADS + h) * L_SEQ + l;
    const float m0 = Mp[s], m1 = Mp[ROWS_TOT + s];
    const float l0 = Lp[s], l1 = Lp[ROWS_TOT + s];
    const float M  = fmaxf(m0, m1);
    const float w0 = __expf(m0 - M);
    const float w1 = __expf(m1 - M);
    const float inv = 1.0f / (l0 * w0 + l1 * w1);
    const float f0 = w0 * inv;
    const float f1 = w1 * inv;
    const size_t o = (size_t)row * 512 + c8 * 8;
    const ushort4 a0 = *(const ushort4*)&O01[o];
    const ushort4 a1 = *(const ushort4*)&O01[o + 4];
    const ushort4 c0 = *(const ushort4*)&O01[PERBL + o];
    const ushort4 c1 = *(const ushort4*)&O01[PERBL + o + 4];
    ushort4 r0, r1;
    r0.x = f2bf(bf2f(a0.x) * f0 + bf2f(c0.x) * f1);
    r0.y = f2bf(bf2f(a0.y) * f0 + bf2f(c0.y) * f1);
    r0.z = f2bf(bf2f(a0.z) * f0 + bf2f(c0.z) * f1);
    r0.w = f2bf(bf2f(a0.w) * f0 + bf2f(c0.w) * f1);
    r1.x = f2bf(bf2f(a1.x) * f0 + bf2f(c1.x) * f1);
    r1.y = f2bf(bf2f(a1.y) * f0 + bf2f(c1.y) * f1);
    r1.z = f2bf(bf2f(a1.z) * f0 + bf2f(c1.z) * f1);
    r1.w = f2bf(bf2f(a1.w) * f0 + bf2f(c1.w) * f1);
    *(ushort4*)&at[o]     = r0;
    *(ushort4*)&at[o + 4] = r1;
}

// ==================================================================
// Output projection via bf16 MFMA + bias + residual. A in registers
// upfront, B reg-double-buffered (same discipline as qkv_mfma).
// grid (36, 8, 2), block 256.
__global__ __launch_bounds__(256) void out_mfma(
    const ushort* __restrict__ at, const ushort* __restrict__ wb,
    const float* __restrict__ bo, const float* __restrict__ x,
    float* __restrict__ y)
{
    __shared__ __align__(16) ushort Bs[1024 * 8];   // 16 KB, fragment-major
    const int l0 = blockIdx.x * 64;
    const int o0 = blockIdx.y * 64;
    const int b  = blockIdx.z;
    const int t = threadIdx.x, w = t >> 6, lane = t & 63;
    const int n16 = lane & 15, q4 = lane >> 4;

    const ushort* A = at + ((size_t)b * L_SEQ + l0 + w * 16 + n16) * 512 + q4 * 8;
    const ushort* W = wb + (size_t)3 * 262144;

    s8v areg[16];
    #pragma unroll
    for (int i = 0; i < 16; i++) areg[i] = *(const s8v*)&A[i * 32];

    int sOff[4];
    #pragma unroll
    for (int i = 0; i < 4; i++) {
        const int c  = t + 256 * i;
        const int fr = c >> 6, ln = c & 63;
        sOff[i] = (o0 + (fr & 3) * 16 + (ln & 15)) * 512 + (fr >> 2) * 32 + (ln >> 4) * 8;
    }

    s8v breg[4];
    #pragma unroll
    for (int i = 0; i < 4; i++) breg[i] = *(const s8v*)&W[sOff[i]];

    f4v acc[4] = {{0.f,0.f,0.f,0.f},{0.f,0.f,0.f,0.f},{0.f,0.f,0.f,0.f},{0.f,0.f,0.f,0.f}};
    for (int kb = 0; kb < 512; kb += 128) {
        __syncthreads();
        #pragma unroll
        for (int i = 0; i < 4; i++)
            *(s8v*)&Bs[(t + 256 * i) * 8] = breg[i];
        __syncthreads();
        if (kb < 384) {
            #pragma unroll
            for (int i = 0; i < 4; i++)
                breg[i] = *(const s8v*)&W[sOff[i] + kb + 128];
        }
        #pragma unroll
        for (int ks = 0; ks < 4; ks++) {
            const s8v a = areg[(kb >> 5) + ks];
            #pragma unroll
            for (int t4 = 0; t4 < 4; t4++) {
                const s8v bf = *(const s8v*)&Bs[((ks * 4 + t4) * 64 + lane) * 8];
                acc[t4] = __builtin_amdgcn_mfma_f32_16x16x32_bf16(a, bf, acc[t4], 0, 0, 0);
            }
        }
    }

    const int rowbase = l0 + w * 16 + q4 * 4;
    #pragma unroll
    for (int t4 = 0; t4 < 4; t4++) {
        const int o = o0 + t4 * 16 + n16;
        const float bi = bo[o];
        const size_t off = ((size_t)b * CDIM + o) * L_SEQ + rowbase;
        const float4 xv = *(const float4*)&x[off];
        float4 st;
        st.x = acc[t4][0] + bi + xv.x;
        st.y = acc[t4][1] + bi + xv.y;
        st.z = acc[t4][2] + bi + xv.z;
        st.w = acc[t4][3] + bi + xv.w;
        *(float4*)&y[off] = st;
    }
}

// ==================================================================
// LayerNorm over channels. 144 blocks, 32 positions/block (128 B
// coalesced segments), 8 channel-groups x 64 channels.
__global__ __launch_bounds__(256) void ln_kernel(
    float* __restrict__ y, const float* __restrict__ gamma,
    const float* __restrict__ beta)
{
    const int t = threadIdx.x;
    const int p = t & 31;         // position within block
    const int g = t >> 5;         // channel group: 8 groups x 64 ch
    const int pos = blockIdx.x * 32 + p;
    const int b = (pos >= L_SEQ) ? 1 : 0;
    const int l = pos - b * L_SEQ;
    float* col = y + (size_t)b * CDIM * L_SEQ + l;

    float s = 0.f, sq = 0.f;
    for (int c = g * 64; c < g * 64 + 64; c++) {
        const float v = col[(size_t)c * L_SEQ];
        s += v; sq += v * v;
    }
    __shared__ float S1[8][32];
    __shared__ float S2[8][32];
    S1[g][p] = s; S2[g][p] = sq;
    __syncthreads();
    if (t < 32) {
        float ss = 0.f, qq = 0.f;
        #pragma unroll
        for (int gg = 0; gg < 8; gg++) { ss += S1[gg][t]; qq += S2[gg][t]; }
        const float mu = ss * (1.0f / CDIM);
        const float var = qq * (1.0f / CDIM) - mu * mu;
        S1[0][t] = mu;
        S2[0][t] = rsqrtf(var + 1e-5f);
    }
    __syncthreads();
    const float mu = S1[0][p];
    const float rs = S2[0][p];
    for (int c = g * 64; c < g * 64 + 64; c++) {
        const float v = col[(size_t)c * L_SEQ];
        col[(size_t)c * L_SEQ] = (v - mu) * rs * gamma[c] + beta[c];
    }
}

// ==================================================================
extern "C" void kernel_launch(void* const* d_in, const int* in_sizes, int n_in,
                              void* d_out, int out_size, void* d_ws, size_t ws_size,
                              hipStream_t stream) {
    const float* x    = (const float*)d_in[0];
    const int* mask   = (const int*)d_in[1];
    const float* pos  = (const float*)d_in[2];
    const float* Wq   = (const float*)d_in[3];
    const float* bq   = (const float*)d_in[4];
    const float* Wk   = (const float*)d_in[5];
    const float* bk   = (const float*)d_in[6];
    const float* Wv   = (const float*)d_in[7];
    const float* bv   = (const float*)d_in[8];
    const float* Wo   = (const float*)d_in[9];
    const float* bo   = (const float*)d_in[10];
    const float* rel  = (const float*)d_in[11];
    const float* gam  = (const float*)d_in[12];
    const float* bet  = (const float*)d_in[13];

    // workspace layout (31.0 MB total, proven safe):
    ushort* qw  = (ushort*)d_ws;
    ushort* kw  = qw + PERBL;
    ushort* vw  = kw + PERBL;
    ushort* xtw = vw + PERBL;
    ushort* wbw = xtw + PERBL;
    ushort* Opart = wbw + (size_t)4 * 512 * 512;
    float* Mpart = (float*)(Opart + 2 * PERBL);
    float* Lpart = Mpart + 2 * ROWS_TOT;
    ushort* attnT = xtw;                      // xt dead after qkv_mfma
    float* y = (float*)d_out;

    prep_w<<<dim3(1024), 256, 0, stream>>>(Wq, Wk, Wv, Wo, wbw);

    xpose<<<dim3(L_SEQ / 64, CDIM / 64, 2), 256, 0, stream>>>(x, pos, xtw);

    qkv_mfma<<<dim3(L_SEQ / 64, CDIM / 64, 2), 256, 0, stream>>>(
        xtw, wbw, bq, bk, bv, qw, kw, vw);

    flash_attn_mfma<<<dim3(1152), 256, 0, stream>>>(qw, kw, vw, mask, rel,
                                                    Opart, Mpart, Lpart);

    combine_kernel<<<dim3(1152), 256, 0, stream>>>(Opart, Mpart, Lpart, attnT);

    out_mfma<<<dim3(L_SEQ / 64, CDIM / 64, 2), 256, 0, stream>>>(
        attnT, wbw, bo, x, y);

    ln_kernel<<<(2 * L_SEQ) / 32, 256, 0, stream>>>(y, gam, bet);
}